// Round 1
// baseline (1968.480 us; speedup 1.0000x reference)
//
#include <hip/hip_runtime.h>
#include <hip/hip_bf16.h>

// ---------------------------------------------------------------------------
// GIN encoder, fp32 baseline.
// h = x@W0+b0; 4x { agg = scatter(h,src->dst); m = MLP(h+agg); h += m }; pool; head.
// GEMMs are register-blocked VALU fp32 (no fp32 MFMA on CDNA4).
// ---------------------------------------------------------------------------

#define TM 32   // nodes per block tile

__global__ __launch_bounds__(256) void k_encoder(const float* __restrict__ x,
                                                 const float* __restrict__ W0,
                                                 const float* __restrict__ b0,
                                                 float* __restrict__ h, int n)
{
    __shared__ float sx[TM][128];
    const int t = threadIdx.x;
    const int node0 = blockIdx.x * TM;

    const float4* x4 = (const float4*)x;
    float4* sx4 = (float4*)&sx[0][0];
    for (int i = t; i < TM * 32; i += 256) {
        int m = i >> 5, q = i & 31;
        int node = node0 + m;
        float4 v = make_float4(0.f, 0.f, 0.f, 0.f);
        if (node < n) v = x4[(size_t)node * 32 + q];
        sx4[i] = v;
    }
    __syncthreads();

    const int cg = t & 15;        // float4-column group: columns cg*4..+3 and 64+cg*4..+3
    const int mg = t >> 4;        // 0..15
    const int m0 = mg * 2;

    const float4* W4 = (const float4*)W0;   // row = 32 float4
    float acc[2][8];
#pragma unroll
    for (int i = 0; i < 2; i++)
#pragma unroll
        for (int j = 0; j < 8; j++) acc[i][j] = 0.f;

    for (int k = 0; k < 128; k++) {
        float4 wa = W4[k * 32 + cg];
        float4 wb = W4[k * 32 + 16 + cg];
#pragma unroll
        for (int i = 0; i < 2; i++) {
            float xv = sx[m0 + i][k];
            acc[i][0] += xv * wa.x; acc[i][1] += xv * wa.y;
            acc[i][2] += xv * wa.z; acc[i][3] += xv * wa.w;
            acc[i][4] += xv * wb.x; acc[i][5] += xv * wb.y;
            acc[i][6] += xv * wb.z; acc[i][7] += xv * wb.w;
        }
    }

    const float4* b4 = (const float4*)b0;
    float4 ba = b4[cg], bb = b4[16 + cg];
    float4* h4 = (float4*)h;
#pragma unroll
    for (int i = 0; i < 2; i++) {
        int node = node0 + m0 + i;
        if (node < n) {
            float4 oa = make_float4(acc[i][0] + ba.x, acc[i][1] + ba.y,
                                    acc[i][2] + ba.z, acc[i][3] + ba.w);
            float4 ob = make_float4(acc[i][4] + bb.x, acc[i][5] + bb.y,
                                    acc[i][6] + bb.z, acc[i][7] + bb.w);
            h4[(size_t)node * 32 + cg] = oa;
            h4[(size_t)node * 32 + 16 + cg] = ob;
        }
    }
}

__global__ __launch_bounds__(256) void k_scatter(const float* __restrict__ h,
                                                 const int* __restrict__ src,
                                                 const int* __restrict__ dst,
                                                 float* __restrict__ agg, int nE)
{
    int wid = (int)((blockIdx.x * 256u + threadIdx.x) >> 6);
    int lane = threadIdx.x & 63;
    if (wid >= nE) return;
    int s = src[wid];
    int d = dst[wid];
    float v0 = h[(size_t)s * 128 + lane];
    float v1 = h[(size_t)s * 128 + 64 + lane];
    atomicAdd(&agg[(size_t)d * 128 + lane], v0);
    atomicAdd(&agg[(size_t)d * 128 + 64 + lane], v1);
}

__global__ __launch_bounds__(256) void k_layer(
    const float* __restrict__ h_in, const float* __restrict__ agg,
    const float* __restrict__ W1, const float* __restrict__ b1,
    const float* __restrict__ g1, const float* __restrict__ be1,
    const float* __restrict__ mu1, const float* __restrict__ va1,
    const float* __restrict__ W2, const float* __restrict__ b2,
    const float* __restrict__ g2, const float* __restrict__ be2,
    const float* __restrict__ mu2, const float* __restrict__ va2,
    float* __restrict__ h_out, int n)
{
    __shared__ float sIn[TM][128];    // h + agg
    __shared__ float sMid[TM][256];   // MLP hidden after BN+ReLU
    const int t = threadIdx.x;
    const int node0 = blockIdx.x * TM;

    // ---- stage input tile: in = h + agg ----
    const float4* hi4 = (const float4*)h_in;
    const float4* ag4 = (const float4*)agg;
    float4* sIn4 = (float4*)&sIn[0][0];
    for (int i = t; i < TM * 32; i += 256) {
        int m = i >> 5, q = i & 31;
        int node = node0 + m;
        float4 v = make_float4(0.f, 0.f, 0.f, 0.f);
        if (node < n) {
            float4 a = hi4[(size_t)node * 32 + q];
            float4 b = ag4[(size_t)node * 32 + q];
            v = make_float4(a.x + b.x, a.y + b.y, a.z + b.z, a.w + b.w);
        }
        sIn4[i] = v;
    }
    __syncthreads();

    // ---- phase 1: mid = ReLU(BN1(in @ W1 + b1)), Cout = 256, K = 128 ----
    {
        const int cg = t & 31;     // columns cg*4..+3 and 128+cg*4..+3
        const int mg = t >> 5;     // 0..7
        const int m0 = mg * 4;
        const float4* W4 = (const float4*)W1;   // row = 64 float4
        float acc[4][8];
#pragma unroll
        for (int i = 0; i < 4; i++)
#pragma unroll
            for (int j = 0; j < 8; j++) acc[i][j] = 0.f;

        for (int k = 0; k < 128; k++) {
            float4 wa = W4[k * 64 + cg];
            float4 wb = W4[k * 64 + 32 + cg];
#pragma unroll
            for (int i = 0; i < 4; i++) {
                float xv = sIn[m0 + i][k];
                acc[i][0] += xv * wa.x; acc[i][1] += xv * wa.y;
                acc[i][2] += xv * wa.z; acc[i][3] += xv * wa.w;
                acc[i][4] += xv * wb.x; acc[i][5] += xv * wb.y;
                acc[i][6] += xv * wb.z; acc[i][7] += xv * wb.w;
            }
        }
#pragma unroll
        for (int j = 0; j < 8; j++) {
            int c = (j < 4) ? (cg * 4 + j) : (128 + cg * 4 + (j - 4));
            float sc = g1[c] * rsqrtf(va1[c] + 1e-5f);
            float sh = (b1[c] - mu1[c]) * sc + be1[c];
#pragma unroll
            for (int i = 0; i < 4; i++)
                sMid[m0 + i][c] = fmaxf(acc[i][j] * sc + sh, 0.f);
        }
    }
    __syncthreads();

    // ---- phase 2: m = ReLU(BN2(mid @ W2 + b2)); h_out = h_in + m. Cout=128, K=256 ----
    {
        const int cg = t & 15;     // columns cg*4..+3 and 64+cg*4..+3
        const int mg = t >> 4;     // 0..15
        const int m0 = mg * 2;
        const float4* W4 = (const float4*)W2;   // row = 32 float4
        float acc[2][8];
#pragma unroll
        for (int i = 0; i < 2; i++)
#pragma unroll
            for (int j = 0; j < 8; j++) acc[i][j] = 0.f;

        for (int k = 0; k < 256; k++) {
            float4 wa = W4[k * 32 + cg];
            float4 wb = W4[k * 32 + 16 + cg];
#pragma unroll
            for (int i = 0; i < 2; i++) {
                float xv = sMid[m0 + i][k];
                acc[i][0] += xv * wa.x; acc[i][1] += xv * wa.y;
                acc[i][2] += xv * wa.z; acc[i][3] += xv * wa.w;
                acc[i][4] += xv * wb.x; acc[i][5] += xv * wb.y;
                acc[i][6] += xv * wb.z; acc[i][7] += xv * wb.w;
            }
        }

        const float4* hi4b = (const float4*)h_in;
        float4* ho4 = (float4*)h_out;
#pragma unroll
        for (int i = 0; i < 2; i++) {
            int node = node0 + m0 + i;
            if (node < n) {
                float4 ha = hi4b[(size_t)node * 32 + cg];
                float4 hb = hi4b[(size_t)node * 32 + 16 + cg];
                float o[8];
#pragma unroll
                for (int j = 0; j < 8; j++) {
                    int c = (j < 4) ? (cg * 4 + j) : (64 + cg * 4 + (j - 4));
                    float sc = g2[c] * rsqrtf(va2[c] + 1e-5f);
                    float sh = (b2[c] - mu2[c]) * sc + be2[c];
                    o[j] = fmaxf(acc[i][j] * sc + sh, 0.f);
                }
                float4 oa = make_float4(ha.x + o[0], ha.y + o[1], ha.z + o[2], ha.w + o[3]);
                float4 ob = make_float4(hb.x + o[4], hb.y + o[5], hb.z + o[6], hb.w + o[7]);
                ho4[(size_t)node * 32 + cg] = oa;
                ho4[(size_t)node * 32 + 16 + cg] = ob;
            }
        }
    }
}

__global__ __launch_bounds__(256) void k_pool(const float* __restrict__ h,
                                              const int* __restrict__ batch,
                                              float* __restrict__ pooled, int n)
{
    int wid = (int)((blockIdx.x * 256u + threadIdx.x) >> 6);
    int lane = threadIdx.x & 63;
    if (wid >= n) return;
    int g = batch[wid];
    atomicAdd(&pooled[(size_t)g * 128 + lane], h[(size_t)wid * 128 + lane]);
    atomicAdd(&pooled[(size_t)g * 128 + 64 + lane], h[(size_t)wid * 128 + 64 + lane]);
}

__global__ __launch_bounds__(128) void k_head(const float* __restrict__ pooled,
                                              const float* __restrict__ W1,
                                              const float* __restrict__ b1,
                                              const float* __restrict__ W2,
                                              const float* __restrict__ b2,
                                              float* __restrict__ out)
{
    __shared__ float sp[128];
    __shared__ float st[128];
    int t = threadIdx.x;
    int g = blockIdx.x;
    sp[t] = pooled[(size_t)g * 128 + t];
    __syncthreads();
    float a = 0.f;
    for (int k = 0; k < 128; k++) a += sp[k] * W1[k * 128 + t];
    st[t] = fmaxf(a + b1[t], 0.f);
    __syncthreads();
    float o = 0.f;
    for (int k = 0; k < 128; k++) o += st[k] * W2[k * 128 + t];
    out[(size_t)g * 128 + t] = o + b2[t];
}

extern "C" void kernel_launch(void* const* d_in, const int* in_sizes, int n_in,
                              void* d_out, int out_size, void* d_ws, size_t ws_size,
                              hipStream_t stream)
{
    const float* x     = (const float*)d_in[0];
    const int*   ei    = (const int*)d_in[1];
    const int*   batch = (const int*)d_in[2];
    const float* W0    = (const float*)d_in[3];
    const float* b0    = (const float*)d_in[4];
    const float* mlpW1 = (const float*)d_in[5];
    const float* mlpb1 = (const float*)d_in[6];
    const float* bn1g  = (const float*)d_in[7];
    const float* bn1b  = (const float*)d_in[8];
    const float* bn1m  = (const float*)d_in[9];
    const float* bn1v  = (const float*)d_in[10];
    const float* mlpW2 = (const float*)d_in[11];
    const float* mlpb2 = (const float*)d_in[12];
    const float* ng    = (const float*)d_in[13];
    const float* nb    = (const float*)d_in[14];
    const float* nm    = (const float*)d_in[15];
    const float* nv    = (const float*)d_in[16];
    const float* W1    = (const float*)d_in[17];
    const float* b1    = (const float*)d_in[18];
    const float* W2    = (const float*)d_in[19];
    const float* b2    = (const float*)d_in[20];
    float* out = (float*)d_out;

    const int N = in_sizes[0] / 128;
    const int E = in_sizes[1] / 2;
    const int G = out_size / 128;
    const int* srcv = ei;
    const int* dstv = ei + E;

    float* ws = (float*)d_ws;
    float* h0     = ws;
    float* h1     = ws + (size_t)N * 128;
    float* agg    = ws + (size_t)2 * N * 128;
    float* pooled = ws + (size_t)3 * N * 128;

    const int nodeBlocks = (N + TM - 1) / TM;

    k_encoder<<<nodeBlocks, 256, 0, stream>>>(x, W0, b0, h0, N);

    float* hc = h0;
    float* hn = h1;
    for (int l = 0; l < 4; l++) {
        hipMemsetAsync(agg, 0, (size_t)N * 128 * sizeof(float), stream);
        k_scatter<<<(E + 3) / 4, 256, 0, stream>>>(hc, srcv, dstv, agg, E);
        k_layer<<<nodeBlocks, 256, 0, stream>>>(
            hc, agg,
            mlpW1 + (size_t)l * 128 * 256, mlpb1 + (size_t)l * 256,
            bn1g + (size_t)l * 256, bn1b + (size_t)l * 256,
            bn1m + (size_t)l * 256, bn1v + (size_t)l * 256,
            mlpW2 + (size_t)l * 256 * 128, mlpb2 + (size_t)l * 128,
            ng + (size_t)l * 128, nb + (size_t)l * 128,
            nm + (size_t)l * 128, nv + (size_t)l * 128,
            hn, N);
        float* tmp = hc; hc = hn; hn = tmp;
    }

    hipMemsetAsync(pooled, 0, (size_t)G * 128 * sizeof(float), stream);
    k_pool<<<(N + 3) / 4, 256, 0, stream>>>(hc, batch, pooled, N);
    k_head<<<G, 128, 0, stream>>>(pooled, W1, b1, W2, b2, out);
}

// Round 2
// 1390.779 us; speedup vs baseline: 1.4154x; 1.4154x over previous
//
#include <hip/hip_runtime.h>
#include <hip/hip_bf16.h>

// ---------------------------------------------------------------------------
// GIN encoder, fp32, CSR-gather aggregation (no atomic scatter).
// Per call: build CSR (hist/scan/fill), h = x@W0+b0,
// 4x { layer kernel: gather neighbors + MLP + BN + ReLU + residual }, pool, head.
// ---------------------------------------------------------------------------

#define TM 32   // nodes per block tile

__global__ __launch_bounds__(256) void k_hist(const int* __restrict__ dst,
                                              int* __restrict__ deg, int nE)
{
    int i = blockIdx.x * 256 + threadIdx.x;
    if (i < nE) atomicAdd(&deg[dst[i]], 1);
}

__global__ __launch_bounds__(1024) void k_scan(const int* __restrict__ deg,
                                               int* __restrict__ rowptr,
                                               int* __restrict__ cursor, int n)
{
    __shared__ int s[1024];
    const int t = threadIdx.x;
    const int C = (n + 1023) >> 10;
    const int lo = t * C;
    const int hi = min(lo + C, n);
    int sum = 0;
    for (int i = lo; i < hi; i++) sum += deg[i];
    s[t] = sum;
    __syncthreads();
    for (int off = 1; off < 1024; off <<= 1) {
        int v = (t >= off) ? s[t - off] : 0;
        __syncthreads();
        s[t] += v;
        __syncthreads();
    }
    int run = (t == 0) ? 0 : s[t - 1];
    for (int i = lo; i < hi; i++) {
        rowptr[i] = run;
        cursor[i] = run;
        run += deg[i];
    }
    if (t == 1023) rowptr[n] = run;
}

__global__ __launch_bounds__(256) void k_fill(const int* __restrict__ src,
                                              const int* __restrict__ dst,
                                              int* __restrict__ cursor,
                                              int* __restrict__ adj, int nE)
{
    int i = blockIdx.x * 256 + threadIdx.x;
    if (i < nE) {
        int pos = atomicAdd(&cursor[dst[i]], 1);
        adj[pos] = src[i];
    }
}

__global__ __launch_bounds__(256) void k_encoder(const float* __restrict__ x,
                                                 const float* __restrict__ W0,
                                                 const float* __restrict__ b0,
                                                 float* __restrict__ h, int n)
{
    __shared__ float sx[TM][128];
    const int t = threadIdx.x;
    const int node0 = blockIdx.x * TM;

    const float4* x4 = (const float4*)x;
    float4* sx4 = (float4*)&sx[0][0];
    for (int i = t; i < TM * 32; i += 256) {
        int m = i >> 5, q = i & 31;
        int node = node0 + m;
        float4 v = make_float4(0.f, 0.f, 0.f, 0.f);
        if (node < n) v = x4[(size_t)node * 32 + q];
        sx4[i] = v;
    }
    __syncthreads();

    const int cg = t & 15;
    const int mg = t >> 4;
    const int m0 = mg * 2;

    const float4* W4 = (const float4*)W0;   // row = 32 float4
    float acc[2][8];
#pragma unroll
    for (int i = 0; i < 2; i++)
#pragma unroll
        for (int j = 0; j < 8; j++) acc[i][j] = 0.f;

    for (int k = 0; k < 128; k++) {
        float4 wa = W4[k * 32 + cg];
        float4 wb = W4[k * 32 + 16 + cg];
#pragma unroll
        for (int i = 0; i < 2; i++) {
            float xv = sx[m0 + i][k];
            acc[i][0] += xv * wa.x; acc[i][1] += xv * wa.y;
            acc[i][2] += xv * wa.z; acc[i][3] += xv * wa.w;
            acc[i][4] += xv * wb.x; acc[i][5] += xv * wb.y;
            acc[i][6] += xv * wb.z; acc[i][7] += xv * wb.w;
        }
    }

    const float4* b4 = (const float4*)b0;
    float4 ba = b4[cg], bb = b4[16 + cg];
    float4* h4 = (float4*)h;
#pragma unroll
    for (int i = 0; i < 2; i++) {
        int node = node0 + m0 + i;
        if (node < n) {
            float4 oa = make_float4(acc[i][0] + ba.x, acc[i][1] + ba.y,
                                    acc[i][2] + ba.z, acc[i][3] + ba.w);
            float4 ob = make_float4(acc[i][4] + bb.x, acc[i][5] + bb.y,
                                    acc[i][6] + bb.z, acc[i][7] + bb.w);
            h4[(size_t)node * 32 + cg] = oa;
            h4[(size_t)node * 32 + 16 + cg] = ob;
        }
    }
}

__global__ __launch_bounds__(256) void k_layer(
    const float* __restrict__ h_in,
    const int* __restrict__ rowptr, const int* __restrict__ adj,
    const float* __restrict__ W1, const float* __restrict__ b1,
    const float* __restrict__ g1, const float* __restrict__ be1,
    const float* __restrict__ mu1, const float* __restrict__ va1,
    const float* __restrict__ W2, const float* __restrict__ b2,
    const float* __restrict__ g2, const float* __restrict__ be2,
    const float* __restrict__ mu2, const float* __restrict__ va2,
    float* __restrict__ h_out, int n)
{
    __shared__ float sIn[TM][128];    // h + sum_{neighbors} h
    __shared__ float sMid[TM][256];   // MLP hidden after BN+ReLU
    const int t = threadIdx.x;
    const int node0 = blockIdx.x * TM;

    // ---- stage input tile: in = h + gather(neighbors) ----
    const float4* h4 = (const float4*)h_in;
    float4* sIn4 = (float4*)&sIn[0][0];
    for (int idx = t; idx < TM * 32; idx += 256) {
        int m = idx >> 5, col = idx & 31;
        int node = node0 + m;
        float4 acc = make_float4(0.f, 0.f, 0.f, 0.f);
        if (node < n) {
            acc = h4[(size_t)node * 32 + col];
            int e0 = rowptr[node], e1 = rowptr[node + 1];
            for (int e = e0; e < e1; e++) {
                int s = adj[e];
                float4 v = h4[(size_t)s * 32 + col];
                acc.x += v.x; acc.y += v.y; acc.z += v.z; acc.w += v.w;
            }
        }
        sIn4[idx] = acc;
    }
    __syncthreads();

    // ---- phase 1: mid = ReLU(BN1(in @ W1 + b1)), Cout = 256, K = 128 ----
    {
        const int cg = t & 31;
        const int mg = t >> 5;
        const int m0 = mg * 4;
        const float4* W4 = (const float4*)W1;   // row = 64 float4
        float acc[4][8];
#pragma unroll
        for (int i = 0; i < 4; i++)
#pragma unroll
            for (int j = 0; j < 8; j++) acc[i][j] = 0.f;

        for (int k = 0; k < 128; k++) {
            float4 wa = W4[k * 64 + cg];
            float4 wb = W4[k * 64 + 32 + cg];
#pragma unroll
            for (int i = 0; i < 4; i++) {
                float xv = sIn[m0 + i][k];
                acc[i][0] += xv * wa.x; acc[i][1] += xv * wa.y;
                acc[i][2] += xv * wa.z; acc[i][3] += xv * wa.w;
                acc[i][4] += xv * wb.x; acc[i][5] += xv * wb.y;
                acc[i][6] += xv * wb.z; acc[i][7] += xv * wb.w;
            }
        }
#pragma unroll
        for (int j = 0; j < 8; j++) {
            int c = (j < 4) ? (cg * 4 + j) : (128 + cg * 4 + (j - 4));
            float sc = g1[c] * rsqrtf(va1[c] + 1e-5f);
            float sh = (b1[c] - mu1[c]) * sc + be1[c];
#pragma unroll
            for (int i = 0; i < 4; i++)
                sMid[m0 + i][c] = fmaxf(acc[i][j] * sc + sh, 0.f);
        }
    }
    __syncthreads();

    // ---- phase 2: m = ReLU(BN2(mid @ W2 + b2)); h_out = h_in + m ----
    {
        const int cg = t & 15;
        const int mg = t >> 4;
        const int m0 = mg * 2;
        const float4* W4 = (const float4*)W2;   // row = 32 float4
        float acc[2][8];
#pragma unroll
        for (int i = 0; i < 2; i++)
#pragma unroll
            for (int j = 0; j < 8; j++) acc[i][j] = 0.f;

        for (int k = 0; k < 256; k++) {
            float4 wa = W4[k * 32 + cg];
            float4 wb = W4[k * 32 + 16 + cg];
#pragma unroll
            for (int i = 0; i < 2; i++) {
                float xv = sMid[m0 + i][k];
                acc[i][0] += xv * wa.x; acc[i][1] += xv * wa.y;
                acc[i][2] += xv * wa.z; acc[i][3] += xv * wa.w;
                acc[i][4] += xv * wb.x; acc[i][5] += xv * wb.y;
                acc[i][6] += xv * wb.z; acc[i][7] += xv * wb.w;
            }
        }

        const float4* hi4b = (const float4*)h_in;
        float4* ho4 = (float4*)h_out;
#pragma unroll
        for (int i = 0; i < 2; i++) {
            int node = node0 + m0 + i;
            if (node < n) {
                float4 ha = hi4b[(size_t)node * 32 + cg];
                float4 hb = hi4b[(size_t)node * 32 + 16 + cg];
                float o[8];
#pragma unroll
                for (int j = 0; j < 8; j++) {
                    int c = (j < 4) ? (cg * 4 + j) : (64 + cg * 4 + (j - 4));
                    float sc = g2[c] * rsqrtf(va2[c] + 1e-5f);
                    float sh = (b2[c] - mu2[c]) * sc + be2[c];
                    o[j] = fmaxf(acc[i][j] * sc + sh, 0.f);
                }
                float4 oa = make_float4(ha.x + o[0], ha.y + o[1], ha.z + o[2], ha.w + o[3]);
                float4 ob = make_float4(hb.x + o[4], hb.y + o[5], hb.z + o[6], hb.w + o[7]);
                ho4[(size_t)node * 32 + cg] = oa;
                ho4[(size_t)node * 32 + 16 + cg] = ob;
            }
        }
    }
}

__global__ __launch_bounds__(256) void k_pool(const float* __restrict__ h,
                                              const int* __restrict__ batch,
                                              float* __restrict__ pooled, int n)
{
    int wid = (int)((blockIdx.x * 256u + threadIdx.x) >> 6);
    int lane = threadIdx.x & 63;
    if (wid >= n) return;
    int g = batch[wid];
    atomicAdd(&pooled[(size_t)g * 128 + lane], h[(size_t)wid * 128 + lane]);
    atomicAdd(&pooled[(size_t)g * 128 + 64 + lane], h[(size_t)wid * 128 + 64 + lane]);
}

__global__ __launch_bounds__(128) void k_head(const float* __restrict__ pooled,
                                              const float* __restrict__ W1,
                                              const float* __restrict__ b1,
                                              const float* __restrict__ W2,
                                              const float* __restrict__ b2,
                                              float* __restrict__ out)
{
    __shared__ float sp[128];
    __shared__ float st[128];
    int t = threadIdx.x;
    int g = blockIdx.x;
    sp[t] = pooled[(size_t)g * 128 + t];
    __syncthreads();
    float a = 0.f;
    for (int k = 0; k < 128; k++) a += sp[k] * W1[k * 128 + t];
    st[t] = fmaxf(a + b1[t], 0.f);
    __syncthreads();
    float o = 0.f;
    for (int k = 0; k < 128; k++) o += st[k] * W2[k * 128 + t];
    out[(size_t)g * 128 + t] = o + b2[t];
}

extern "C" void kernel_launch(void* const* d_in, const int* in_sizes, int n_in,
                              void* d_out, int out_size, void* d_ws, size_t ws_size,
                              hipStream_t stream)
{
    const float* x     = (const float*)d_in[0];
    const int*   ei    = (const int*)d_in[1];
    const int*   batch = (const int*)d_in[2];
    const float* W0    = (const float*)d_in[3];
    const float* b0    = (const float*)d_in[4];
    const float* mlpW1 = (const float*)d_in[5];
    const float* mlpb1 = (const float*)d_in[6];
    const float* bn1g  = (const float*)d_in[7];
    const float* bn1b  = (const float*)d_in[8];
    const float* bn1m  = (const float*)d_in[9];
    const float* bn1v  = (const float*)d_in[10];
    const float* mlpW2 = (const float*)d_in[11];
    const float* mlpb2 = (const float*)d_in[12];
    const float* ng    = (const float*)d_in[13];
    const float* nb    = (const float*)d_in[14];
    const float* nm    = (const float*)d_in[15];
    const float* nv    = (const float*)d_in[16];
    const float* W1    = (const float*)d_in[17];
    const float* b1    = (const float*)d_in[18];
    const float* W2    = (const float*)d_in[19];
    const float* b2    = (const float*)d_in[20];
    float* out = (float*)d_out;

    const int N = in_sizes[0] / 128;
    const int E = in_sizes[1] / 2;
    const int G = out_size / 128;
    const int* srcv = ei;
    const int* dstv = ei + E;

    // workspace layout
    float* ws = (float*)d_ws;
    float* h0     = ws;                                  // N*128 f32
    float* h1     = ws + (size_t)N * 128;                // N*128 f32
    float* pooled = ws + (size_t)2 * N * 128;            // G*128 f32
    int* ints   = (int*)(pooled + (size_t)G * 128);
    int* deg    = ints;                                  // N
    int* rowptr = ints + N;                              // N+1
    int* cursor = ints + 2 * N + 1;                      // N
    int* adj    = ints + 3 * N + 1;                      // E

    const int nodeBlocks = (N + TM - 1) / TM;

    // ---- CSR build ----
    hipMemsetAsync(deg, 0, (size_t)N * sizeof(int), stream);
    k_hist<<<(E + 255) / 256, 256, 0, stream>>>(dstv, deg, E);
    k_scan<<<1, 1024, 0, stream>>>(deg, rowptr, cursor, N);
    k_fill<<<(E + 255) / 256, 256, 0, stream>>>(srcv, dstv, cursor, adj, E);

    // ---- encoder ----
    k_encoder<<<nodeBlocks, 256, 0, stream>>>(x, W0, b0, h0, N);

    // ---- layers ----
    float* hc = h0;
    float* hn = h1;
    for (int l = 0; l < 4; l++) {
        k_layer<<<nodeBlocks, 256, 0, stream>>>(
            hc, rowptr, adj,
            mlpW1 + (size_t)l * 128 * 256, mlpb1 + (size_t)l * 256,
            bn1g + (size_t)l * 256, bn1b + (size_t)l * 256,
            bn1m + (size_t)l * 256, bn1v + (size_t)l * 256,
            mlpW2 + (size_t)l * 256 * 128, mlpb2 + (size_t)l * 128,
            ng + (size_t)l * 128, nb + (size_t)l * 128,
            nm + (size_t)l * 128, nv + (size_t)l * 128,
            hn, N);
        float* tmp = hc; hc = hn; hn = tmp;
    }

    // ---- pool + head ----
    hipMemsetAsync(pooled, 0, (size_t)G * 128 * sizeof(float), stream);
    k_pool<<<(N + 3) / 4, 256, 0, stream>>>(hc, batch, pooled, N);
    k_head<<<G, 128, 0, stream>>>(pooled, W1, b1, W2, b2, out);
}

// Round 3
// 930.443 us; speedup vs baseline: 2.1156x; 1.4947x over previous
//
#include <hip/hip_runtime.h>
#include <hip/hip_bf16.h>

// ---------------------------------------------------------------------------
// GIN encoder. fp32 residual stream h (in-place) + bf16 mirror hb for gather.
// GEMMs via mfma_f32_16x16x32_bf16 with pre-packed B-fragment weights.
// CSR gather, wave-per-node, adj prefetch. Run-length pooling.
// ---------------------------------------------------------------------------

typedef short bf16x8 __attribute__((ext_vector_type(8)));
typedef float f32x4 __attribute__((ext_vector_type(4)));

__device__ __forceinline__ float bs2f(unsigned short u) {
    return __uint_as_float(((unsigned)u) << 16);
}
__device__ __forceinline__ unsigned short f2bs(float f) {
    __hip_bfloat16 h = __float2bfloat16(f);
    return *reinterpret_cast<unsigned short*>(&h);
}

// ---------------- CSR build ----------------
__global__ __launch_bounds__(256) void k_hist(const int* __restrict__ dst,
                                              int* __restrict__ deg, int nE)
{
    int i = blockIdx.x * 256 + threadIdx.x;
    if (i < nE) atomicAdd(&deg[dst[i]], 1);
}

__global__ __launch_bounds__(1024) void k_scan(const int* __restrict__ deg,
                                               int* __restrict__ rowptr,
                                               int* __restrict__ cursor, int n)
{
    __shared__ int s[1024];
    const int t = threadIdx.x;
    const int C = (n + 1023) >> 10;
    const int lo = t * C;
    const int hi = min(lo + C, n);
    int sum = 0;
    for (int i = lo; i < hi; i++) sum += deg[i];
    s[t] = sum;
    __syncthreads();
    for (int off = 1; off < 1024; off <<= 1) {
        int v = (t >= off) ? s[t - off] : 0;
        __syncthreads();
        s[t] += v;
        __syncthreads();
    }
    int run = (t == 0) ? 0 : s[t - 1];
    for (int i = lo; i < hi; i++) {
        rowptr[i] = run;
        cursor[i] = run;
        run += deg[i];
    }
    if (t == 1023) rowptr[n] = run;
}

__global__ __launch_bounds__(256) void k_fill(const int* __restrict__ src,
                                              const int* __restrict__ dst,
                                              int* __restrict__ cursor,
                                              int* __restrict__ adj, int nE)
{
    int i = blockIdx.x * 256 + threadIdx.x;
    if (i < nE) {
        int pos = atomicAdd(&cursor[dst[i]], 1);
        adj[pos] = src[i];
    }
}

// ---------------- weight packing: W[K][N] fp32 -> B-fragment bf16 ----------
// frag (nt,kt): P[((l*Nt+nt)*Kt+kt)*64 + lane][j] = W_l[kt*32+(lane>>4)*8+j][nt*16+(lane&15)]
__global__ __launch_bounds__(256) void k_pack(const float* __restrict__ W,
                                              short* __restrict__ P,
                                              int Lnum, int Kt, int Nt)
{
    int id = blockIdx.x * 256 + threadIdx.x;
    int total = Lnum * Nt * Kt * 64;
    if (id >= total) return;
    int lane = id & 63;
    int t = id >> 6;
    int kt = t % Kt; t /= Kt;
    int nt = t % Nt; int l = t / Nt;
    int K = Kt * 32, N = Nt * 16;
    const float* Wl = W + (size_t)l * K * N;
    int n = nt * 16 + (lane & 15);
    int kbase = kt * 32 + (lane >> 4) * 8;
    short o[8];
#pragma unroll
    for (int j = 0; j < 8; j++)
        o[j] = (short)f2bs(Wl[(size_t)(kbase + j) * N + n]);
    bf16x8 v;
#pragma unroll
    for (int j = 0; j < 8; j++) v[j] = o[j];
    *(bf16x8*)(P + (size_t)id * 8) = v;
}

// ---------------- encoder: h = x@W0 + b0 (fp32 VALU), writes h + hb -------
__global__ __launch_bounds__(256) void k_encoder(const float* __restrict__ x,
                                                 const float* __restrict__ W0,
                                                 const float* __restrict__ b0,
                                                 float* __restrict__ h,
                                                 unsigned short* __restrict__ hb,
                                                 int n)
{
    __shared__ float sx[32][128];
    const int t = threadIdx.x;
    const int node0 = blockIdx.x * 32;

    const float4* x4 = (const float4*)x;
    float4* sx4 = (float4*)&sx[0][0];
    for (int i = t; i < 32 * 32; i += 256) {
        int m = i >> 5, q = i & 31;
        int node = node0 + m;
        float4 v = make_float4(0.f, 0.f, 0.f, 0.f);
        if (node < n) v = x4[(size_t)node * 32 + q];
        sx4[i] = v;
    }
    __syncthreads();

    const int cg = t & 15;
    const int mg = t >> 4;
    const int m0 = mg * 2;

    const float4* W4 = (const float4*)W0;
    float acc[2][8];
#pragma unroll
    for (int i = 0; i < 2; i++)
#pragma unroll
        for (int j = 0; j < 8; j++) acc[i][j] = 0.f;

    for (int k = 0; k < 128; k++) {
        float4 wa = W4[k * 32 + cg];
        float4 wb = W4[k * 32 + 16 + cg];
#pragma unroll
        for (int i = 0; i < 2; i++) {
            float xv = sx[m0 + i][k];
            acc[i][0] += xv * wa.x; acc[i][1] += xv * wa.y;
            acc[i][2] += xv * wa.z; acc[i][3] += xv * wa.w;
            acc[i][4] += xv * wb.x; acc[i][5] += xv * wb.y;
            acc[i][6] += xv * wb.z; acc[i][7] += xv * wb.w;
        }
    }

    const float4* b4 = (const float4*)b0;
    float4 ba = b4[cg], bb = b4[16 + cg];
    float4* h4 = (float4*)h;
#pragma unroll
    for (int i = 0; i < 2; i++) {
        int node = node0 + m0 + i;
        if (node < n) {
            float4 oa = make_float4(acc[i][0] + ba.x, acc[i][1] + ba.y,
                                    acc[i][2] + ba.z, acc[i][3] + ba.w);
            float4 ob = make_float4(acc[i][4] + bb.x, acc[i][5] + bb.y,
                                    acc[i][6] + bb.z, acc[i][7] + bb.w);
            h4[(size_t)node * 32 + cg] = oa;
            h4[(size_t)node * 32 + 16 + cg] = ob;
            ushort4 pa, pb;
            pa.x = f2bs(oa.x); pa.y = f2bs(oa.y); pa.z = f2bs(oa.z); pa.w = f2bs(oa.w);
            pb.x = f2bs(ob.x); pb.y = f2bs(ob.y); pb.z = f2bs(ob.z); pb.w = f2bs(ob.w);
            ((ushort4*)hb)[(size_t)node * 32 + cg] = pa;
            ((ushort4*)hb)[(size_t)node * 32 + 16 + cg] = pb;
        }
    }
}

// ---------------- fused GIN layer -----------------------------------------
__global__ __launch_bounds__(256, 6) void k_layer(
    float* __restrict__ h, const unsigned short* __restrict__ hb_in,
    unsigned short* __restrict__ hb_out,
    const int* __restrict__ rowptr, const int* __restrict__ adj,
    const short* __restrict__ pW1, const float* __restrict__ b1,
    const float* __restrict__ g1, const float* __restrict__ be1,
    const float* __restrict__ mu1, const float* __restrict__ va1,
    const short* __restrict__ pW2, const float* __restrict__ b2,
    const float* __restrict__ g2, const float* __restrict__ be2,
    const float* __restrict__ mu2, const float* __restrict__ va2,
    int n)
{
    __shared__ unsigned short sIn[32][136];    // bf16(h + sum nbr), pad 8
    __shared__ unsigned short sMid[32][264];   // bf16 MLP hidden, pad 8
    const int t = threadIdx.x;
    const int w = t >> 6;
    const int L = t & 63;
    const int node0 = blockIdx.x * 32;

    // ---- gather: wave w handles nodes w*8..w*8+7; lane covers cols 2L,2L+1
    const ushort2* hb2 = (const ushort2*)hb_in;
    const float2* h2 = (const float2*)h;
    for (int i = 0; i < 8; i++) {
        int m = w * 8 + i;
        int node = node0 + m;
        float a0 = 0.f, a1 = 0.f;
        if (node < n) {
            float2 hs = h2[(size_t)node * 64 + L];
            a0 = hs.x; a1 = hs.y;
            int e0 = rowptr[node], e1 = rowptr[node + 1];
            if (e0 < e1) {
                int sNext = adj[e0];
                for (int e = e0; e < e1; e++) {
                    int sv = sNext;
                    sNext = adj[(e + 1 < e1) ? (e + 1) : e];
                    ushort2 v = hb2[(size_t)sv * 64 + L];
                    a0 += bs2f(v.x);
                    a1 += bs2f(v.y);
                }
            }
        }
        ushort2 o;
        o.x = f2bs(a0);
        o.y = f2bs(a1);
        *(ushort2*)&sIn[m][2 * L] = o;
    }
    __syncthreads();

    const int quad = L >> 4;
    const int l16 = L & 15;
    const int m0 = (w & 1) * 16;

    // ---- phase 1: sMid = relu(BN1(sIn @ W1 + b1)), 32x256, K=128 ----
    {
        bf16x8 a[4];
#pragma unroll
        for (int kt = 0; kt < 4; kt++)
            a[kt] = *(const bf16x8*)&sIn[m0 + l16][kt * 32 + quad * 8];
        const bf16x8* base1 = (const bf16x8*)pW1;
        const int ntBase = (w >> 1) * 8;
        for (int nt = ntBase; nt < ntBase + 8; nt++) {
            f32x4 acc = {0.f, 0.f, 0.f, 0.f};
#pragma unroll
            for (int kt = 0; kt < 4; kt++) {
                bf16x8 b = base1[(size_t)(nt * 4 + kt) * 64 + L];
                acc = __builtin_amdgcn_mfma_f32_16x16x32_bf16(a[kt], b, acc, 0, 0, 0);
            }
            int c = nt * 16 + l16;
            float sc = g1[c] * rsqrtf(va1[c] + 1e-5f);
            float sh = (b1[c] - mu1[c]) * sc + be1[c];
#pragma unroll
            for (int r = 0; r < 4; r++) {
                float v = fmaxf(acc[r] * sc + sh, 0.f);
                sMid[m0 + quad * 4 + r][c] = f2bs(v);
            }
        }
    }
    __syncthreads();

    // ---- phase 2: m = relu(BN2(sMid @ W2 + b2)); h += m (in-place) ----
    {
        f32x4 acc[4];
#pragma unroll
        for (int i = 0; i < 4; i++) acc[i] = (f32x4){0.f, 0.f, 0.f, 0.f};
        const bf16x8* base2 = (const bf16x8*)pW2;
        const int ntBase = (w >> 1) * 4;
#pragma unroll
        for (int kh = 0; kh < 2; kh++) {
            bf16x8 a[4];
#pragma unroll
            for (int kt = 0; kt < 4; kt++)
                a[kt] = *(const bf16x8*)&sMid[m0 + l16][(kh * 4 + kt) * 32 + quad * 8];
#pragma unroll
            for (int i = 0; i < 4; i++) {
#pragma unroll
                for (int kt = 0; kt < 4; kt++) {
                    bf16x8 b = base2[(size_t)((ntBase + i) * 8 + kh * 4 + kt) * 64 + L];
                    acc[i] = __builtin_amdgcn_mfma_f32_16x16x32_bf16(a[kt], b, acc[i], 0, 0, 0);
                }
            }
        }
#pragma unroll
        for (int i = 0; i < 4; i++) {
            int c = (ntBase + i) * 16 + l16;
            float sc = g2[c] * rsqrtf(va2[c] + 1e-5f);
            float sh = (b2[c] - mu2[c]) * sc + be2[c];
#pragma unroll
            for (int r = 0; r < 4; r++) {
                int node = node0 + m0 + quad * 4 + r;
                if (node < n) {
                    float o = fmaxf(acc[i][r] * sc + sh, 0.f);
                    float nh = h[(size_t)node * 128 + c] + o;
                    h[(size_t)node * 128 + c] = nh;
                    hb_out[(size_t)node * 128 + c] = f2bs(nh);
                }
            }
        }
    }
}

// ---------------- pooling: run-length over sorted batch -------------------
__global__ __launch_bounds__(256) void k_pool(const float* __restrict__ h,
                                              const int* __restrict__ batch,
                                              float* __restrict__ pooled, int n)
{
    int c = threadIdx.x & 127;
    int half = threadIdx.x >> 7;
    int base = blockIdx.x * 128 + half * 64;
    float acc = 0.f;
    int curg = -1;
    for (int i = 0; i < 64; i++) {
        int node = base + i;
        if (node >= n) break;
        int g = batch[node];
        if (g != curg) {
            if (curg >= 0) atomicAdd(&pooled[(size_t)curg * 128 + c], acc);
            curg = g;
            acc = 0.f;
        }
        acc += h[(size_t)node * 128 + c];
    }
    if (curg >= 0) atomicAdd(&pooled[(size_t)curg * 128 + c], acc);
}

__global__ __launch_bounds__(128) void k_head(const float* __restrict__ pooled,
                                              const float* __restrict__ W1,
                                              const float* __restrict__ b1,
                                              const float* __restrict__ W2,
                                              const float* __restrict__ b2,
                                              float* __restrict__ out)
{
    __shared__ float sp[128];
    __shared__ float st[128];
    int t = threadIdx.x;
    int g = blockIdx.x;
    sp[t] = pooled[(size_t)g * 128 + t];
    __syncthreads();
    float a = 0.f;
    for (int k = 0; k < 128; k++) a += sp[k] * W1[k * 128 + t];
    st[t] = fmaxf(a + b1[t], 0.f);
    __syncthreads();
    float o = 0.f;
    for (int k = 0; k < 128; k++) o += st[k] * W2[k * 128 + t];
    out[(size_t)g * 128 + t] = o + b2[t];
}

extern "C" void kernel_launch(void* const* d_in, const int* in_sizes, int n_in,
                              void* d_out, int out_size, void* d_ws, size_t ws_size,
                              hipStream_t stream)
{
    const float* x     = (const float*)d_in[0];
    const int*   ei    = (const int*)d_in[1];
    const int*   batch = (const int*)d_in[2];
    const float* W0    = (const float*)d_in[3];
    const float* b0    = (const float*)d_in[4];
    const float* mlpW1 = (const float*)d_in[5];
    const float* mlpb1 = (const float*)d_in[6];
    const float* bn1g  = (const float*)d_in[7];
    const float* bn1b  = (const float*)d_in[8];
    const float* bn1m  = (const float*)d_in[9];
    const float* bn1v  = (const float*)d_in[10];
    const float* mlpW2 = (const float*)d_in[11];
    const float* mlpb2 = (const float*)d_in[12];
    const float* ng    = (const float*)d_in[13];
    const float* nb    = (const float*)d_in[14];
    const float* nm    = (const float*)d_in[15];
    const float* nv    = (const float*)d_in[16];
    const float* W1    = (const float*)d_in[17];
    const float* b1    = (const float*)d_in[18];
    const float* W2    = (const float*)d_in[19];
    const float* b2    = (const float*)d_in[20];
    float* out = (float*)d_out;

    const int N = in_sizes[0] / 128;
    const int E = in_sizes[1] / 2;
    const int G = out_size / 128;
    const int* srcv = ei;
    const int* dstv = ei + E;

    // workspace layout
    float* h      = (float*)d_ws;                               // N*128 f32
    float* pooled = h + (size_t)N * 128;                        // G*128 f32
    unsigned short* hb0 = (unsigned short*)(pooled + (size_t)G * 128); // N*128
    unsigned short* hb1 = hb0 + (size_t)N * 128;                // N*128
    short* pW1 = (short*)(hb1 + (size_t)N * 128);               // 4*128*256
    short* pW2 = pW1 + 131072;                                  // 4*256*128
    int* ints  = (int*)(pW2 + 131072);
    int* deg    = ints;
    int* rowptr = ints + N;
    int* cursor = ints + 2 * N + 1;
    int* adj    = ints + 3 * N + 1;

    const int nodeBlocks = (N + 31) / 32;

    // ---- CSR build + weight packing ----
    hipMemsetAsync(deg, 0, (size_t)N * sizeof(int), stream);
    k_hist<<<(E + 255) / 256, 256, 0, stream>>>(dstv, deg, E);
    k_scan<<<1, 1024, 0, stream>>>(deg, rowptr, cursor, N);
    k_fill<<<(E + 255) / 256, 256, 0, stream>>>(srcv, dstv, cursor, adj, E);
    k_pack<<<(4 * 16 * 4 * 64 + 255) / 256, 256, 0, stream>>>(mlpW1, pW1, 4, 4, 16);
    k_pack<<<(4 * 8 * 8 * 64 + 255) / 256, 256, 0, stream>>>(mlpW2, pW2, 4, 8, 8);

    // ---- encoder ----
    k_encoder<<<nodeBlocks, 256, 0, stream>>>(x, W0, b0, h, hb0, N);

    // ---- layers (h updated in place; hb ping-pong) ----
    unsigned short* hc = hb0;
    unsigned short* hn = hb1;
    for (int l = 0; l < 4; l++) {
        k_layer<<<nodeBlocks, 256, 0, stream>>>(
            h, hc, hn, rowptr, adj,
            pW1 + (size_t)l * 32768, mlpb1 + (size_t)l * 256,
            bn1g + (size_t)l * 256, bn1b + (size_t)l * 256,
            bn1m + (size_t)l * 256, bn1v + (size_t)l * 256,
            pW2 + (size_t)l * 32768, mlpb2 + (size_t)l * 128,
            ng + (size_t)l * 128, nb + (size_t)l * 128,
            nm + (size_t)l * 128, nv + (size_t)l * 128,
            N);
        unsigned short* tmp = hc; hc = hn; hn = tmp;
    }

    // ---- pool + head ----
    hipMemsetAsync(pooled, 0, (size_t)G * 128 * sizeof(float), stream);
    k_pool<<<(N + 127) / 128, 256, 0, stream>>>(h, batch, pooled, N);
    k_head<<<G, 128, 0, stream>>>(pooled, W1, b1, W2, b2, out);
}

// Round 4
// 652.018 us; speedup vs baseline: 3.0191x; 1.4270x over previous
//
#include <hip/hip_runtime.h>
#include <hip/hip_bf16.h>

// ---------------------------------------------------------------------------
// GIN encoder. fp32 residual stream h (in-place) + bf16 mirror hb for gather.
// All GEMMs via mfma_f32_16x16x32_bf16 with pre-packed B-fragment weights.
// CSR gather with 4-wide unrolled edge loop (4 loads in flight).
// ---------------------------------------------------------------------------

typedef short bf16x8 __attribute__((ext_vector_type(8)));
typedef float f32x4 __attribute__((ext_vector_type(4)));

__device__ __forceinline__ float bs2f(unsigned short u) {
    return __uint_as_float(((unsigned)u) << 16);
}
__device__ __forceinline__ unsigned short f2bs(float f) {
    __hip_bfloat16 h = __float2bfloat16(f);
    return *reinterpret_cast<unsigned short*>(&h);
}

// ---------------- CSR build ----------------
__global__ __launch_bounds__(256) void k_hist(const int* __restrict__ dst,
                                              int* __restrict__ deg, int nE)
{
    int i = blockIdx.x * 256 + threadIdx.x;
    if (i < nE) atomicAdd(&deg[dst[i]], 1);
}

__global__ __launch_bounds__(1024) void k_scan(const int* __restrict__ deg,
                                               int* __restrict__ rowptr,
                                               int* __restrict__ cursor, int n)
{
    __shared__ int s[1024];
    const int t = threadIdx.x;
    const int C = (n + 1023) >> 10;
    const int lo = t * C;
    const int hi = min(lo + C, n);
    int sum = 0;
    for (int i = lo; i < hi; i++) sum += deg[i];
    s[t] = sum;
    __syncthreads();
    for (int off = 1; off < 1024; off <<= 1) {
        int v = (t >= off) ? s[t - off] : 0;
        __syncthreads();
        s[t] += v;
        __syncthreads();
    }
    int run = (t == 0) ? 0 : s[t - 1];
    for (int i = lo; i < hi; i++) {
        rowptr[i] = run;
        cursor[i] = run;
        run += deg[i];
    }
    if (t == 1023) rowptr[n] = run;
}

__global__ __launch_bounds__(256) void k_fill(const int* __restrict__ src,
                                              const int* __restrict__ dst,
                                              int* __restrict__ cursor,
                                              int* __restrict__ adj, int nE)
{
    int i = blockIdx.x * 256 + threadIdx.x;
    if (i < nE) {
        int pos = atomicAdd(&cursor[dst[i]], 1);
        adj[pos] = src[i];
    }
}

// ---------------- weight packing: W[K][N] fp32 -> B-fragment bf16 ----------
// frag (nt,kt): P[((l*Nt+nt)*Kt+kt)*64 + lane][j] = W_l[kt*32+(lane>>4)*8+j][nt*16+(lane&15)]
__global__ __launch_bounds__(256) void k_pack(const float* __restrict__ W,
                                              short* __restrict__ P,
                                              int Lnum, int Kt, int Nt)
{
    int id = blockIdx.x * 256 + threadIdx.x;
    int total = Lnum * Nt * Kt * 64;
    if (id >= total) return;
    int lane = id & 63;
    int t = id >> 6;
    int kt = t % Kt; t /= Kt;
    int nt = t % Nt; int l = t / Nt;
    int K = Kt * 32, N = Nt * 16;
    const float* Wl = W + (size_t)l * K * N;
    int n = nt * 16 + (lane & 15);
    int kbase = kt * 32 + (lane >> 4) * 8;
    bf16x8 v;
#pragma unroll
    for (int j = 0; j < 8; j++)
        v[j] = (short)f2bs(Wl[(size_t)(kbase + j) * N + n]);
    *(bf16x8*)(P + (size_t)id * 8) = v;
}

// ---------------- encoder: h = x@W0 + b0 via MFMA, writes h + hb ----------
__global__ __launch_bounds__(256) void k_encoder(const float* __restrict__ x,
                                                 const short* __restrict__ pW0,
                                                 const float* __restrict__ b0,
                                                 float* __restrict__ h,
                                                 unsigned short* __restrict__ hb,
                                                 int n)
{
    __shared__ unsigned short sX[32][136];
    const int t = threadIdx.x;
    const int w = t >> 6;
    const int L = t & 63;
    const int node0 = blockIdx.x * 32;

    const float4* x4 = (const float4*)x;
    for (int i = t; i < 32 * 32; i += 256) {
        int m = i >> 5, cgi = i & 31;
        int node = node0 + m;
        float4 v = make_float4(0.f, 0.f, 0.f, 0.f);
        if (node < n) v = x4[(size_t)node * 32 + cgi];
        ushort4 p;
        p.x = f2bs(v.x); p.y = f2bs(v.y); p.z = f2bs(v.z); p.w = f2bs(v.w);
        *(ushort4*)&sX[m][cgi * 4] = p;
    }
    __syncthreads();

    const int quad = L >> 4;
    const int l16 = L & 15;
    const int m0 = (w & 1) * 16;
    const int ntBase = (w >> 1) * 4;

    bf16x8 a[4];
#pragma unroll
    for (int kt = 0; kt < 4; kt++)
        a[kt] = *(const bf16x8*)&sX[m0 + l16][kt * 32 + quad * 8];

    const bf16x8* base = (const bf16x8*)pW0;
#pragma unroll
    for (int nt = ntBase; nt < ntBase + 4; nt++) {
        f32x4 acc = {0.f, 0.f, 0.f, 0.f};
#pragma unroll
        for (int kt = 0; kt < 4; kt++) {
            bf16x8 b = base[(size_t)(nt * 4 + kt) * 64 + L];
            acc = __builtin_amdgcn_mfma_f32_16x16x32_bf16(a[kt], b, acc, 0, 0, 0);
        }
        int c = nt * 16 + l16;
        float bc = b0[c];
#pragma unroll
        for (int r = 0; r < 4; r++) {
            int node = node0 + m0 + quad * 4 + r;
            if (node < n) {
                float val = acc[r] + bc;
                h[(size_t)node * 128 + c] = val;
                hb[(size_t)node * 128 + c] = f2bs(val);
            }
        }
    }
}

// ---------------- fused GIN layer -----------------------------------------
__global__ __launch_bounds__(256, 6) void k_layer(
    float* __restrict__ h, const unsigned short* __restrict__ hb_in,
    unsigned short* __restrict__ hb_out,
    const int* __restrict__ rowptr, const int* __restrict__ adj,
    const short* __restrict__ pW1, const float* __restrict__ b1,
    const float* __restrict__ g1, const float* __restrict__ be1,
    const float* __restrict__ mu1, const float* __restrict__ va1,
    const short* __restrict__ pW2, const float* __restrict__ b2,
    const float* __restrict__ g2, const float* __restrict__ be2,
    const float* __restrict__ mu2, const float* __restrict__ va2,
    int n)
{
    __shared__ unsigned short sIn[32][136];    // bf16(h + sum nbr), pad 8
    __shared__ unsigned short sMid[32][264];   // bf16 MLP hidden, pad 8
    const int t = threadIdx.x;
    const int w = t >> 6;
    const int L = t & 63;
    const int node0 = blockIdx.x * 32;

    // ---- gather: wave w -> nodes w*8..w*8+7; lane covers cols 2L,2L+1.
    // 4-wide unrolled edge loop: 4 independent loads in flight.
    const ushort2* hb2 = (const ushort2*)hb_in;
    for (int i = 0; i < 8; i++) {
        int m = w * 8 + i;
        int node = node0 + m;
        float a0 = 0.f, a1 = 0.f;
        if (node < n) {
            ushort2 self = hb2[(size_t)node * 64 + L];
            a0 = bs2f(self.x); a1 = bs2f(self.y);
            float p0 = 0.f, p1 = 0.f, q0 = 0.f, q1 = 0.f, r0 = 0.f, r1 = 0.f;
            int e0 = rowptr[node], e1 = rowptr[node + 1];
            int e = e0;
            for (; e + 4 <= e1; e += 4) {
                int s0 = adj[e], s1 = adj[e + 1], s2 = adj[e + 2], s3 = adj[e + 3];
                ushort2 v0 = hb2[(size_t)s0 * 64 + L];
                ushort2 v1 = hb2[(size_t)s1 * 64 + L];
                ushort2 v2 = hb2[(size_t)s2 * 64 + L];
                ushort2 v3 = hb2[(size_t)s3 * 64 + L];
                a0 += bs2f(v0.x); a1 += bs2f(v0.y);
                p0 += bs2f(v1.x); p1 += bs2f(v1.y);
                q0 += bs2f(v2.x); q1 += bs2f(v2.y);
                r0 += bs2f(v3.x); r1 += bs2f(v3.y);
            }
            for (; e < e1; e++) {
                int sv = adj[e];
                ushort2 v = hb2[(size_t)sv * 64 + L];
                a0 += bs2f(v.x); a1 += bs2f(v.y);
            }
            a0 += p0 + q0 + r0;
            a1 += p1 + q1 + r1;
        }
        ushort2 o;
        o.x = f2bs(a0);
        o.y = f2bs(a1);
        *(ushort2*)&sIn[m][2 * L] = o;
    }
    __syncthreads();

    const int quad = L >> 4;
    const int l16 = L & 15;
    const int m0 = (w & 1) * 16;

    // ---- phase 1: sMid = relu(BN1(sIn @ W1 + b1)), 32x256, K=128 ----
    {
        bf16x8 a[4];
#pragma unroll
        for (int kt = 0; kt < 4; kt++)
            a[kt] = *(const bf16x8*)&sIn[m0 + l16][kt * 32 + quad * 8];
        const bf16x8* base1 = (const bf16x8*)pW1;
        const int ntBase = (w >> 1) * 8;
        for (int nt = ntBase; nt < ntBase + 8; nt++) {
            f32x4 acc = {0.f, 0.f, 0.f, 0.f};
#pragma unroll
            for (int kt = 0; kt < 4; kt++) {
                bf16x8 b = base1[(size_t)(nt * 4 + kt) * 64 + L];
                acc = __builtin_amdgcn_mfma_f32_16x16x32_bf16(a[kt], b, acc, 0, 0, 0);
            }
            int c = nt * 16 + l16;
            float sc = g1[c] * rsqrtf(va1[c] + 1e-5f);
            float sh = (b1[c] - mu1[c]) * sc + be1[c];
#pragma unroll
            for (int r = 0; r < 4; r++) {
                float v = fmaxf(acc[r] * sc + sh, 0.f);
                sMid[m0 + quad * 4 + r][c] = f2bs(v);
            }
        }
    }
    __syncthreads();

    // ---- phase 2: m = relu(BN2(sMid @ W2 + b2)); h += m (in-place) ----
    {
        f32x4 acc[4];
#pragma unroll
        for (int i = 0; i < 4; i++) acc[i] = (f32x4){0.f, 0.f, 0.f, 0.f};
        const bf16x8* base2 = (const bf16x8*)pW2;
        const int ntBase = (w >> 1) * 4;
#pragma unroll
        for (int kh = 0; kh < 2; kh++) {
            bf16x8 a[4];
#pragma unroll
            for (int kt = 0; kt < 4; kt++)
                a[kt] = *(const bf16x8*)&sMid[m0 + l16][(kh * 4 + kt) * 32 + quad * 8];
#pragma unroll
            for (int i = 0; i < 4; i++) {
#pragma unroll
                for (int kt = 0; kt < 4; kt++) {
                    bf16x8 b = base2[(size_t)((ntBase + i) * 8 + kh * 4 + kt) * 64 + L];
                    acc[i] = __builtin_amdgcn_mfma_f32_16x16x32_bf16(a[kt], b, acc[i], 0, 0, 0);
                }
            }
        }
        const bool wb = (hb_out != nullptr);
#pragma unroll
        for (int i = 0; i < 4; i++) {
            int c = (ntBase + i) * 16 + l16;
            float sc = g2[c] * rsqrtf(va2[c] + 1e-5f);
            float sh = (b2[c] - mu2[c]) * sc + be2[c];
#pragma unroll
            for (int r = 0; r < 4; r++) {
                int node = node0 + m0 + quad * 4 + r;
                if (node < n) {
                    float o = fmaxf(acc[i][r] * sc + sh, 0.f);
                    float nh = h[(size_t)node * 128 + c] + o;
                    h[(size_t)node * 128 + c] = nh;
                    if (wb) hb_out[(size_t)node * 128 + c] = f2bs(nh);
                }
            }
        }
    }
}

// ---------------- pooling: run-length over sorted batch -------------------
__global__ __launch_bounds__(256) void k_pool(const float* __restrict__ h,
                                              const int* __restrict__ batch,
                                              float* __restrict__ pooled, int n)
{
    int c = threadIdx.x & 127;
    int half = threadIdx.x >> 7;
    int base = blockIdx.x * 128 + half * 64;
    float acc = 0.f;
    int curg = -1;
    for (int i = 0; i < 64; i++) {
        int node = base + i;
        if (node >= n) break;
        int g = batch[node];
        if (g != curg) {
            if (curg >= 0) atomicAdd(&pooled[(size_t)curg * 128 + c], acc);
            curg = g;
            acc = 0.f;
        }
        acc += h[(size_t)node * 128 + c];
    }
    if (curg >= 0) atomicAdd(&pooled[(size_t)curg * 128 + c], acc);
}

__global__ __launch_bounds__(128) void k_head(const float* __restrict__ pooled,
                                              const float* __restrict__ W1,
                                              const float* __restrict__ b1,
                                              const float* __restrict__ W2,
                                              const float* __restrict__ b2,
                                              float* __restrict__ out)
{
    __shared__ float sp[128];
    __shared__ float st[128];
    int t = threadIdx.x;
    int g = blockIdx.x;
    sp[t] = pooled[(size_t)g * 128 + t];
    __syncthreads();
    float a = 0.f;
    for (int k = 0; k < 128; k++) a += sp[k] * W1[k * 128 + t];
    st[t] = fmaxf(a + b1[t], 0.f);
    __syncthreads();
    float o = 0.f;
    for (int k = 0; k < 128; k++) o += st[k] * W2[k * 128 + t];
    out[(size_t)g * 128 + t] = o + b2[t];
}

extern "C" void kernel_launch(void* const* d_in, const int* in_sizes, int n_in,
                              void* d_out, int out_size, void* d_ws, size_t ws_size,
                              hipStream_t stream)
{
    const float* x     = (const float*)d_in[0];
    const int*   ei    = (const int*)d_in[1];
    const int*   batch = (const int*)d_in[2];
    const float* W0    = (const float*)d_in[3];
    const float* b0    = (const float*)d_in[4];
    const float* mlpW1 = (const float*)d_in[5];
    const float* mlpb1 = (const float*)d_in[6];
    const float* bn1g  = (const float*)d_in[7];
    const float* bn1b  = (const float*)d_in[8];
    const float* bn1m  = (const float*)d_in[9];
    const float* bn1v  = (const float*)d_in[10];
    const float* mlpW2 = (const float*)d_in[11];
    const float* mlpb2 = (const float*)d_in[12];
    const float* ng    = (const float*)d_in[13];
    const float* nb    = (const float*)d_in[14];
    const float* nm    = (const float*)d_in[15];
    const float* nv    = (const float*)d_in[16];
    const float* W1    = (const float*)d_in[17];
    const float* b1    = (const float*)d_in[18];
    const float* W2    = (const float*)d_in[19];
    const float* b2    = (const float*)d_in[20];
    float* out = (float*)d_out;

    const int N = in_sizes[0] / 128;
    const int E = in_sizes[1] / 2;
    const int G = out_size / 128;
    const int* srcv = ei;
    const int* dstv = ei + E;

    // workspace layout
    float* h      = (float*)d_ws;                               // N*128 f32
    float* pooled = h + (size_t)N * 128;                        // G*128 f32
    unsigned short* hb0 = (unsigned short*)(pooled + (size_t)G * 128); // N*128
    unsigned short* hb1 = hb0 + (size_t)N * 128;                // N*128
    short* pW1 = (short*)(hb1 + (size_t)N * 128);               // 4*128*256
    short* pW2 = pW1 + 131072;                                  // 4*256*128
    short* pW0 = pW2 + 131072;                                  // 128*128
    int* ints  = (int*)(pW0 + 16384);
    int* deg    = ints;
    int* rowptr = ints + N;
    int* cursor = ints + 2 * N + 1;
    int* adj    = ints + 3 * N + 1;

    const int nodeBlocks = (N + 31) / 32;

    // ---- CSR build + weight packing ----
    hipMemsetAsync(deg, 0, (size_t)N * sizeof(int), stream);
    k_hist<<<(E + 255) / 256, 256, 0, stream>>>(dstv, deg, E);
    k_scan<<<1, 1024, 0, stream>>>(deg, rowptr, cursor, N);
    k_fill<<<(E + 255) / 256, 256, 0, stream>>>(srcv, dstv, cursor, adj, E);
    k_pack<<<(4 * 16 * 4 * 64 + 255) / 256, 256, 0, stream>>>(mlpW1, pW1, 4, 4, 16);
    k_pack<<<(4 * 8 * 8 * 64 + 255) / 256, 256, 0, stream>>>(mlpW2, pW2, 4, 8, 8);
    k_pack<<<(1 * 8 * 4 * 64 + 255) / 256, 256, 0, stream>>>(W0, pW0, 1, 4, 8);

    // ---- encoder ----
    k_encoder<<<nodeBlocks, 256, 0, stream>>>(x, pW0, b0, h, hb0, N);

    // ---- layers (h updated in place; hb ping-pong; last layer skips hb) --
    unsigned short* hc = hb0;
    unsigned short* hn = hb1;
    for (int l = 0; l < 4; l++) {
        k_layer<<<nodeBlocks, 256, 0, stream>>>(
            h, hc, (l == 3) ? nullptr : hn, rowptr, adj,
            pW1 + (size_t)l * 32768, mlpb1 + (size_t)l * 256,
            bn1g + (size_t)l * 256, bn1b + (size_t)l * 256,
            bn1m + (size_t)l * 256, bn1v + (size_t)l * 256,
            pW2 + (size_t)l * 32768, mlpb2 + (size_t)l * 128,
            ng + (size_t)l * 128, nb + (size_t)l * 128,
            nm + (size_t)l * 128, nv + (size_t)l * 128,
            N);
        unsigned short* tmp = hc; hc = hn; hn = tmp;
    }

    // ---- pool + head ----
    hipMemsetAsync(pooled, 0, (size_t)G * 128 * sizeof(float), stream);
    k_pool<<<(N + 127) / 128, 256, 0, stream>>>(h, batch, pooled, N);
    k_head<<<G, 128, 0, stream>>>(pooled, W1, b1, W2, b2, out);
}

// Round 5
// 525.826 us; speedup vs baseline: 3.7436x; 1.2400x over previous
//
#include <hip/hip_runtime.h>
#include <hip/hip_bf16.h>

// ---------------------------------------------------------------------------
// GIN encoder. fp32 residual stream h (in-place) + bf16 mirror hb for gather.
// All GEMMs via mfma_f32_16x16x32_bf16 with pre-packed B-fragment weights.
// CSR gather with 8/4/1 unrolled edge loop. Multi-block 3-phase CSR scan.
// ---------------------------------------------------------------------------

typedef short bf16x8 __attribute__((ext_vector_type(8)));
typedef float f32x4 __attribute__((ext_vector_type(4)));

__device__ __forceinline__ float bs2f(unsigned short u) {
    return __uint_as_float(((unsigned)u) << 16);
}
__device__ __forceinline__ unsigned short f2bs(float f) {
    __hip_bfloat16 h = __float2bfloat16(f);
    return *reinterpret_cast<unsigned short*>(&h);
}

// ---------------- CSR build ----------------
__global__ __launch_bounds__(256) void k_hist(const int* __restrict__ dst,
                                              int* __restrict__ deg, int nE)
{
    int i = blockIdx.x * 256 + threadIdx.x;
    if (i < nE) atomicAdd(&deg[dst[i]], 1);
}

// Phase A: per-256-chunk sums
__global__ __launch_bounds__(256) void k_scanA(const int* __restrict__ deg,
                                               int* __restrict__ partials, int n)
{
    int i = blockIdx.x * 256 + threadIdx.x;
    int v = (i < n) ? deg[i] : 0;
#pragma unroll
    for (int off = 32; off >= 1; off >>= 1) v += __shfl_down(v, off, 64);
    __shared__ int ws[4];
    int wave = threadIdx.x >> 6;
    if ((threadIdx.x & 63) == 0) ws[wave] = v;
    __syncthreads();
    if (threadIdx.x == 0)
        partials[blockIdx.x] = ws[0] + ws[1] + ws[2] + ws[3];
}

// Phase B: exclusive scan of partials (nb <= 256), single block
__global__ __launch_bounds__(256) void k_scanB(int* __restrict__ partials, int nb)
{
    __shared__ int s[256];
    int t = threadIdx.x;
    int v = (t < nb) ? partials[t] : 0;
    s[t] = v;
    __syncthreads();
    for (int off = 1; off < 256; off <<= 1) {
        int u = (t >= off) ? s[t - off] : 0;
        __syncthreads();
        s[t] += u;
        __syncthreads();
    }
    if (t < nb) partials[t] = s[t] - v;   // exclusive
}

// Phase C: block-local exclusive scan + base; write rowptr & cursor
__global__ __launch_bounds__(256) void k_scanC(const int* __restrict__ deg,
                                               const int* __restrict__ partials,
                                               int* __restrict__ rowptr,
                                               int* __restrict__ cursor, int n)
{
    __shared__ int s[256];
    int t = threadIdx.x;
    int i = blockIdx.x * 256 + t;
    int v = (i < n) ? deg[i] : 0;
    s[t] = v;
    __syncthreads();
    for (int off = 1; off < 256; off <<= 1) {
        int u = (t >= off) ? s[t - off] : 0;
        __syncthreads();
        s[t] += u;
        __syncthreads();
    }
    int inc = s[t];
    int base = partials[blockIdx.x];
    if (i < n) {
        int ex = base + inc - v;
        rowptr[i] = ex;
        cursor[i] = ex;
        if (i == n - 1) rowptr[n] = base + inc;
    }
}

__global__ __launch_bounds__(256) void k_fill(const int* __restrict__ src,
                                              const int* __restrict__ dst,
                                              int* __restrict__ cursor,
                                              int* __restrict__ adj, int nE)
{
    int i = blockIdx.x * 256 + threadIdx.x;
    if (i < nE) {
        int pos = atomicAdd(&cursor[dst[i]], 1);
        adj[pos] = src[i];
    }
}

// ---------------- weight packing: W[K][N] fp32 -> B-fragment bf16 ----------
// frag (nt,kt): P[((l*Nt+nt)*Kt+kt)*64 + lane][j] = W_l[kt*32+(lane>>4)*8+j][nt*16+(lane&15)]
__global__ __launch_bounds__(256) void k_pack(const float* __restrict__ W,
                                              short* __restrict__ P,
                                              int Lnum, int Kt, int Nt)
{
    int id = blockIdx.x * 256 + threadIdx.x;
    int total = Lnum * Nt * Kt * 64;
    if (id >= total) return;
    int lane = id & 63;
    int t = id >> 6;
    int kt = t % Kt; t /= Kt;
    int nt = t % Nt; int l = t / Nt;
    int K = Kt * 32, N = Nt * 16;
    const float* Wl = W + (size_t)l * K * N;
    int n = nt * 16 + (lane & 15);
    int kbase = kt * 32 + (lane >> 4) * 8;
    bf16x8 v;
#pragma unroll
    for (int j = 0; j < 8; j++)
        v[j] = (short)f2bs(Wl[(size_t)(kbase + j) * N + n]);
    *(bf16x8*)(P + (size_t)id * 8) = v;
}

// ---------------- encoder: h = x@W0 + b0 via MFMA, writes h + hb ----------
__global__ __launch_bounds__(256) void k_encoder(const float* __restrict__ x,
                                                 const short* __restrict__ pW0,
                                                 const float* __restrict__ b0,
                                                 float* __restrict__ h,
                                                 unsigned short* __restrict__ hb,
                                                 int n)
{
    __shared__ unsigned short sX[32][136];
    const int t = threadIdx.x;
    const int w = t >> 6;
    const int L = t & 63;
    const int node0 = blockIdx.x * 32;

    const float4* x4 = (const float4*)x;
    for (int i = t; i < 32 * 32; i += 256) {
        int m = i >> 5, cgi = i & 31;
        int node = node0 + m;
        float4 v = make_float4(0.f, 0.f, 0.f, 0.f);
        if (node < n) v = x4[(size_t)node * 32 + cgi];
        ushort4 p;
        p.x = f2bs(v.x); p.y = f2bs(v.y); p.z = f2bs(v.z); p.w = f2bs(v.w);
        *(ushort4*)&sX[m][cgi * 4] = p;
    }
    __syncthreads();

    const int quad = L >> 4;
    const int l16 = L & 15;
    const int m0 = (w & 1) * 16;
    const int ntBase = (w >> 1) * 4;

    bf16x8 a[4];
#pragma unroll
    for (int kt = 0; kt < 4; kt++)
        a[kt] = *(const bf16x8*)&sX[m0 + l16][kt * 32 + quad * 8];

    const bf16x8* base = (const bf16x8*)pW0;
#pragma unroll
    for (int nt = ntBase; nt < ntBase + 4; nt++) {
        f32x4 acc = {0.f, 0.f, 0.f, 0.f};
#pragma unroll
        for (int kt = 0; kt < 4; kt++) {
            bf16x8 b = base[(size_t)(nt * 4 + kt) * 64 + L];
            acc = __builtin_amdgcn_mfma_f32_16x16x32_bf16(a[kt], b, acc, 0, 0, 0);
        }
        int c = nt * 16 + l16;
        float bc = b0[c];
#pragma unroll
        for (int r = 0; r < 4; r++) {
            int node = node0 + m0 + quad * 4 + r;
            if (node < n) {
                float val = acc[r] + bc;
                h[(size_t)node * 128 + c] = val;
                hb[(size_t)node * 128 + c] = f2bs(val);
            }
        }
    }
}

// ---------------- fused GIN layer -----------------------------------------
__global__ __launch_bounds__(256, 6) void k_layer(
    float* __restrict__ h, const unsigned short* __restrict__ hb_in,
    unsigned short* __restrict__ hb_out,
    const int* __restrict__ rowptr, const int* __restrict__ adj,
    const short* __restrict__ pW1, const float* __restrict__ b1,
    const float* __restrict__ g1, const float* __restrict__ be1,
    const float* __restrict__ mu1, const float* __restrict__ va1,
    const short* __restrict__ pW2, const float* __restrict__ b2,
    const float* __restrict__ g2, const float* __restrict__ be2,
    const float* __restrict__ mu2, const float* __restrict__ va2,
    int n)
{
    __shared__ unsigned short sIn[32][136];    // bf16(h + sum nbr), pad 8
    __shared__ unsigned short sMid[32][264];   // bf16 MLP hidden, pad 8
    const int t = threadIdx.x;
    const int w = t >> 6;
    const int L = t & 63;
    const int node0 = blockIdx.x * 32;

    // ---- gather: wave w -> nodes w*8..w*8+7; lane covers cols 2L,2L+1.
    // 8/4/1 unroll ladder keeps up to 8 loads in flight.
    const ushort2* hb2 = (const ushort2*)hb_in;
    for (int i = 0; i < 8; i++) {
        int m = w * 8 + i;
        int node = node0 + m;
        float a0 = 0.f, a1 = 0.f;
        if (node < n) {
            ushort2 self = hb2[(size_t)node * 64 + L];
            a0 = bs2f(self.x); a1 = bs2f(self.y);
            float acc0[8], acc1[8];
#pragma unroll
            for (int j = 0; j < 8; j++) { acc0[j] = 0.f; acc1[j] = 0.f; }
            int e0 = rowptr[node], e1 = rowptr[node + 1];
            int e = e0;
            for (; e + 8 <= e1; e += 8) {
                ushort2 v[8];
#pragma unroll
                for (int j = 0; j < 8; j++) v[j] = hb2[(size_t)adj[e + j] * 64 + L];
#pragma unroll
                for (int j = 0; j < 8; j++) { acc0[j] += bs2f(v[j].x); acc1[j] += bs2f(v[j].y); }
            }
            if (e + 4 <= e1) {
                ushort2 v[4];
#pragma unroll
                for (int j = 0; j < 4; j++) v[j] = hb2[(size_t)adj[e + j] * 64 + L];
#pragma unroll
                for (int j = 0; j < 4; j++) { acc0[j] += bs2f(v[j].x); acc1[j] += bs2f(v[j].y); }
                e += 4;
            }
            for (; e < e1; e++) {
                ushort2 v = hb2[(size_t)adj[e] * 64 + L];
                a0 += bs2f(v.x); a1 += bs2f(v.y);
            }
#pragma unroll
            for (int j = 0; j < 8; j++) { a0 += acc0[j]; a1 += acc1[j]; }
        }
        ushort2 o;
        o.x = f2bs(a0);
        o.y = f2bs(a1);
        *(ushort2*)&sIn[m][2 * L] = o;
    }
    __syncthreads();

    const int quad = L >> 4;
    const int l16 = L & 15;
    const int m0 = (w & 1) * 16;

    // ---- phase 1: sMid = relu(BN1(sIn @ W1 + b1)), 32x256, K=128 ----
    {
        bf16x8 a[4];
#pragma unroll
        for (int kt = 0; kt < 4; kt++)
            a[kt] = *(const bf16x8*)&sIn[m0 + l16][kt * 32 + quad * 8];
        const bf16x8* base1 = (const bf16x8*)pW1;
        const int ntBase = (w >> 1) * 8;
        for (int nt = ntBase; nt < ntBase + 8; nt++) {
            f32x4 acc = {0.f, 0.f, 0.f, 0.f};
#pragma unroll
            for (int kt = 0; kt < 4; kt++) {
                bf16x8 b = base1[(size_t)(nt * 4 + kt) * 64 + L];
                acc = __builtin_amdgcn_mfma_f32_16x16x32_bf16(a[kt], b, acc, 0, 0, 0);
            }
            int c = nt * 16 + l16;
            float sc = g1[c] * rsqrtf(va1[c] + 1e-5f);
            float sh = (b1[c] - mu1[c]) * sc + be1[c];
#pragma unroll
            for (int r = 0; r < 4; r++) {
                float v = fmaxf(acc[r] * sc + sh, 0.f);
                sMid[m0 + quad * 4 + r][c] = f2bs(v);
            }
        }
    }
    __syncthreads();

    // ---- phase 2: m = relu(BN2(sMid @ W2 + b2)); h += m (in-place) ----
    {
        f32x4 acc[4];
#pragma unroll
        for (int i = 0; i < 4; i++) acc[i] = (f32x4){0.f, 0.f, 0.f, 0.f};
        const bf16x8* base2 = (const bf16x8*)pW2;
        const int ntBase = (w >> 1) * 4;
#pragma unroll
        for (int kh = 0; kh < 2; kh++) {
            bf16x8 a[4];
#pragma unroll
            for (int kt = 0; kt < 4; kt++)
                a[kt] = *(const bf16x8*)&sMid[m0 + l16][(kh * 4 + kt) * 32 + quad * 8];
#pragma unroll
            for (int i = 0; i < 4; i++) {
#pragma unroll
                for (int kt = 0; kt < 4; kt++) {
                    bf16x8 b = base2[(size_t)((ntBase + i) * 8 + kh * 4 + kt) * 64 + L];
                    acc[i] = __builtin_amdgcn_mfma_f32_16x16x32_bf16(a[kt], b, acc[i], 0, 0, 0);
                }
            }
        }
        const bool wb = (hb_out != nullptr);
#pragma unroll
        for (int i = 0; i < 4; i++) {
            int c = (ntBase + i) * 16 + l16;
            float sc = g2[c] * rsqrtf(va2[c] + 1e-5f);
            float sh = (b2[c] - mu2[c]) * sc + be2[c];
#pragma unroll
            for (int r = 0; r < 4; r++) {
                int node = node0 + m0 + quad * 4 + r;
                if (node < n) {
                    float o = fmaxf(acc[i][r] * sc + sh, 0.f);
                    float nh = h[(size_t)node * 128 + c] + o;
                    h[(size_t)node * 128 + c] = nh;
                    if (wb) hb_out[(size_t)node * 128 + c] = f2bs(nh);
                }
            }
        }
    }
}

// ---------------- pooling: run-length over sorted batch -------------------
__global__ __launch_bounds__(256) void k_pool(const float* __restrict__ h,
                                              const int* __restrict__ batch,
                                              float* __restrict__ pooled, int n)
{
    int c = threadIdx.x & 127;
    int half = threadIdx.x >> 7;
    int base = blockIdx.x * 128 + half * 64;
    float acc = 0.f;
    int curg = -1;
    for (int i = 0; i < 64; i++) {
        int node = base + i;
        if (node >= n) break;
        int g = batch[node];
        if (g != curg) {
            if (curg >= 0) atomicAdd(&pooled[(size_t)curg * 128 + c], acc);
            curg = g;
            acc = 0.f;
        }
        acc += h[(size_t)node * 128 + c];
    }
    if (curg >= 0) atomicAdd(&pooled[(size_t)curg * 128 + c], acc);
}

__global__ __launch_bounds__(128) void k_head(const float* __restrict__ pooled,
                                              const float* __restrict__ W1,
                                              const float* __restrict__ b1,
                                              const float* __restrict__ W2,
                                              const float* __restrict__ b2,
                                              float* __restrict__ out)
{
    __shared__ float sp[128];
    __shared__ float st[128];
    int t = threadIdx.x;
    int g = blockIdx.x;
    sp[t] = pooled[(size_t)g * 128 + t];
    __syncthreads();
    float a = 0.f;
    for (int k = 0; k < 128; k++) a += sp[k] * W1[k * 128 + t];
    st[t] = fmaxf(a + b1[t], 0.f);
    __syncthreads();
    float o = 0.f;
    for (int k = 0; k < 128; k++) o += st[k] * W2[k * 128 + t];
    out[(size_t)g * 128 + t] = o + b2[t];
}

extern "C" void kernel_launch(void* const* d_in, const int* in_sizes, int n_in,
                              void* d_out, int out_size, void* d_ws, size_t ws_size,
                              hipStream_t stream)
{
    const float* x     = (const float*)d_in[0];
    const int*   ei    = (const int*)d_in[1];
    const int*   batch = (const int*)d_in[2];
    const float* W0    = (const float*)d_in[3];
    const float* b0    = (const float*)d_in[4];
    const float* mlpW1 = (const float*)d_in[5];
    const float* mlpb1 = (const float*)d_in[6];
    const float* bn1g  = (const float*)d_in[7];
    const float* bn1b  = (const float*)d_in[8];
    const float* bn1m  = (const float*)d_in[9];
    const float* bn1v  = (const float*)d_in[10];
    const float* mlpW2 = (const float*)d_in[11];
    const float* mlpb2 = (const float*)d_in[12];
    const float* ng    = (const float*)d_in[13];
    const float* nb    = (const float*)d_in[14];
    const float* nm    = (const float*)d_in[15];
    const float* nv    = (const float*)d_in[16];
    const float* W1    = (const float*)d_in[17];
    const float* b1    = (const float*)d_in[18];
    const float* W2    = (const float*)d_in[19];
    const float* b2    = (const float*)d_in[20];
    float* out = (float*)d_out;

    const int N = in_sizes[0] / 128;
    const int E = in_sizes[1] / 2;
    const int G = out_size / 128;
    const int* srcv = ei;
    const int* dstv = ei + E;

    // workspace layout
    float* h      = (float*)d_ws;                               // N*128 f32
    float* pooled = h + (size_t)N * 128;                        // G*128 f32
    unsigned short* hb0 = (unsigned short*)(pooled + (size_t)G * 128); // N*128
    unsigned short* hb1 = hb0 + (size_t)N * 128;                // N*128
    short* pW1 = (short*)(hb1 + (size_t)N * 128);               // 4*128*256
    short* pW2 = pW1 + 131072;                                  // 4*256*128
    short* pW0 = pW2 + 131072;                                  // 128*128
    int* ints  = (int*)(pW0 + 16384);
    int* deg      = ints;
    int* rowptr   = ints + N;
    int* cursor   = ints + 2 * N + 1;
    int* partials = ints + 3 * N + 1;                           // 256
    int* adj      = ints + 3 * N + 1 + 256;                     // E

    const int nodeBlocks = (N + 31) / 32;
    const int nbScan = (N + 255) / 256;

    // ---- CSR build + weight packing ----
    hipMemsetAsync(deg, 0, (size_t)N * sizeof(int), stream);
    k_hist<<<(E + 255) / 256, 256, 0, stream>>>(dstv, deg, E);
    k_scanA<<<nbScan, 256, 0, stream>>>(deg, partials, N);
    k_scanB<<<1, 256, 0, stream>>>(partials, nbScan);
    k_scanC<<<nbScan, 256, 0, stream>>>(deg, partials, rowptr, cursor, N);
    k_fill<<<(E + 255) / 256, 256, 0, stream>>>(srcv, dstv, cursor, adj, E);
    k_pack<<<(4 * 16 * 4 * 64 + 255) / 256, 256, 0, stream>>>(mlpW1, pW1, 4, 4, 16);
    k_pack<<<(4 * 8 * 8 * 64 + 255) / 256, 256, 0, stream>>>(mlpW2, pW2, 4, 8, 8);
    k_pack<<<(1 * 8 * 4 * 64 + 255) / 256, 256, 0, stream>>>(W0, pW0, 1, 4, 8);

    // ---- encoder ----
    k_encoder<<<nodeBlocks, 256, 0, stream>>>(x, pW0, b0, h, hb0, N);

    // ---- layers (h updated in place; hb ping-pong; last layer skips hb) --
    unsigned short* hc = hb0;
    unsigned short* hn = hb1;
    for (int l = 0; l < 4; l++) {
        k_layer<<<nodeBlocks, 256, 0, stream>>>(
            h, hc, (l == 3) ? nullptr : hn, rowptr, adj,
            pW1 + (size_t)l * 32768, mlpb1 + (size_t)l * 256,
            bn1g + (size_t)l * 256, bn1b + (size_t)l * 256,
            bn1m + (size_t)l * 256, bn1v + (size_t)l * 256,
            pW2 + (size_t)l * 32768, mlpb2 + (size_t)l * 128,
            ng + (size_t)l * 128, nb + (size_t)l * 128,
            nm + (size_t)l * 128, nv + (size_t)l * 128,
            N);
        unsigned short* tmp = hc; hc = hn; hn = tmp;
    }

    // ---- pool + head ----
    hipMemsetAsync(pooled, 0, (size_t)G * 128 * sizeof(float), stream);
    k_pool<<<(N + 127) / 128, 256, 0, stream>>>(h, batch, pooled, N);
    k_head<<<G, 128, 0, stream>>>(pooled, W1, b1, W2, b2, out);
}

// Round 6
// 490.969 us; speedup vs baseline: 4.0094x; 1.0710x over previous
//
#include <hip/hip_runtime.h>
#include <hip/hip_bf16.h>

// ---------------------------------------------------------------------------
// GIN encoder. Residual stream kept ONLY in bf16 (hb ping-pong buffers).
// All GEMMs via mfma_f32_16x16x32_bf16 with pre-packed B-fragment weights.
// CSR gather with paired-node interleaved edge loops (8 loads in flight).
// ---------------------------------------------------------------------------

typedef short bf16x8 __attribute__((ext_vector_type(8)));
typedef float f32x4 __attribute__((ext_vector_type(4)));

__device__ __forceinline__ float bs2f(unsigned short u) {
    return __uint_as_float(((unsigned)u) << 16);
}
__device__ __forceinline__ unsigned short f2bs(float f) {
    __hip_bfloat16 h = __float2bfloat16(f);
    return *reinterpret_cast<unsigned short*>(&h);
}

// ---------------- CSR build ----------------
__global__ __launch_bounds__(256) void k_hist(const int* __restrict__ dst,
                                              int* __restrict__ deg, int nE)
{
    int i = blockIdx.x * 256 + threadIdx.x;
    if (i < nE) atomicAdd(&deg[dst[i]], 1);
}

// Phase A: per-256-chunk sums
__global__ __launch_bounds__(256) void k_scanA(const int* __restrict__ deg,
                                               int* __restrict__ partials, int n)
{
    int i = blockIdx.x * 256 + threadIdx.x;
    int v = (i < n) ? deg[i] : 0;
#pragma unroll
    for (int off = 32; off >= 1; off >>= 1) v += __shfl_down(v, off, 64);
    __shared__ int ws[4];
    int wave = threadIdx.x >> 6;
    if ((threadIdx.x & 63) == 0) ws[wave] = v;
    __syncthreads();
    if (threadIdx.x == 0)
        partials[blockIdx.x] = ws[0] + ws[1] + ws[2] + ws[3];
}

// Phase C: local scan of partials + block-local scan of deg; write rowptr/cursor
__global__ __launch_bounds__(256) void k_scanC(const int* __restrict__ deg,
                                               const int* __restrict__ partials,
                                               int* __restrict__ rowptr,
                                               int* __restrict__ cursor,
                                               int n, int nb)
{
    __shared__ int sp[256];
    __shared__ int s[256];
    int t = threadIdx.x;
    // scan partials (exclusive base for this block)
    int pv = (t < nb) ? partials[t] : 0;
    sp[t] = pv;
    __syncthreads();
    for (int off = 1; off < 256; off <<= 1) {
        int u = (t >= off) ? sp[t - off] : 0;
        __syncthreads();
        sp[t] += u;
        __syncthreads();
    }
    int base = (blockIdx.x == 0) ? 0 : sp[blockIdx.x - 1];
    // block-local scan of deg
    int i = blockIdx.x * 256 + t;
    int v = (i < n) ? deg[i] : 0;
    s[t] = v;
    __syncthreads();
    for (int off = 1; off < 256; off <<= 1) {
        int u = (t >= off) ? s[t - off] : 0;
        __syncthreads();
        s[t] += u;
        __syncthreads();
    }
    int inc = s[t];
    if (i < n) {
        int ex = base + inc - v;
        rowptr[i] = ex;
        cursor[i] = ex;
        if (i == n - 1) rowptr[n] = base + inc;
    }
}

__global__ __launch_bounds__(256) void k_fill(const int* __restrict__ src,
                                              const int* __restrict__ dst,
                                              int* __restrict__ cursor,
                                              int* __restrict__ adj, int nE)
{
    int i = blockIdx.x * 256 + threadIdx.x;
    if (i < nE) {
        int pos = atomicAdd(&cursor[dst[i]], 1);
        adj[pos] = src[i];
    }
}

// ---------------- weight packing: W[K][N] fp32 -> B-fragment bf16 ----------
// frag (nt,kt): P[((l*Nt+nt)*Kt+kt)*64 + lane][j] = W_l[kt*32+(lane>>4)*8+j][nt*16+(lane&15)]
__global__ __launch_bounds__(256) void k_pack(const float* __restrict__ W,
                                              short* __restrict__ P,
                                              int Lnum, int Kt, int Nt)
{
    int id = blockIdx.x * 256 + threadIdx.x;
    int total = Lnum * Nt * Kt * 64;
    if (id >= total) return;
    int lane = id & 63;
    int t = id >> 6;
    int kt = t % Kt; t /= Kt;
    int nt = t % Nt; int l = t / Nt;
    int K = Kt * 32, N = Nt * 16;
    const float* Wl = W + (size_t)l * K * N;
    int n = nt * 16 + (lane & 15);
    int kbase = kt * 32 + (lane >> 4) * 8;
    bf16x8 v;
#pragma unroll
    for (int j = 0; j < 8; j++)
        v[j] = (short)f2bs(Wl[(size_t)(kbase + j) * N + n]);
    *(bf16x8*)(P + (size_t)id * 8) = v;
}

// ---------------- encoder: hb = bf16(x@W0 + b0) via MFMA ------------------
__global__ __launch_bounds__(256) void k_encoder(const float* __restrict__ x,
                                                 const short* __restrict__ pW0,
                                                 const float* __restrict__ b0,
                                                 unsigned short* __restrict__ hb,
                                                 int n)
{
    __shared__ unsigned short sX[32][136];
    const int t = threadIdx.x;
    const int w = t >> 6;
    const int L = t & 63;
    const int node0 = blockIdx.x * 32;

    const float4* x4 = (const float4*)x;
    for (int i = t; i < 32 * 32; i += 256) {
        int m = i >> 5, cgi = i & 31;
        int node = node0 + m;
        float4 v = make_float4(0.f, 0.f, 0.f, 0.f);
        if (node < n) v = x4[(size_t)node * 32 + cgi];
        ushort4 p;
        p.x = f2bs(v.x); p.y = f2bs(v.y); p.z = f2bs(v.z); p.w = f2bs(v.w);
        *(ushort4*)&sX[m][cgi * 4] = p;
    }
    __syncthreads();

    const int quad = L >> 4;
    const int l16 = L & 15;
    const int m0 = (w & 1) * 16;
    const int ntBase = (w >> 1) * 4;

    bf16x8 a[4];
#pragma unroll
    for (int kt = 0; kt < 4; kt++)
        a[kt] = *(const bf16x8*)&sX[m0 + l16][kt * 32 + quad * 8];

    const bf16x8* base = (const bf16x8*)pW0;
#pragma unroll
    for (int nt = ntBase; nt < ntBase + 4; nt++) {
        f32x4 acc = {0.f, 0.f, 0.f, 0.f};
#pragma unroll
        for (int kt = 0; kt < 4; kt++) {
            bf16x8 b = base[(size_t)(nt * 4 + kt) * 64 + L];
            acc = __builtin_amdgcn_mfma_f32_16x16x32_bf16(a[kt], b, acc, 0, 0, 0);
        }
        int c = nt * 16 + l16;
        float bc = b0[c];
#pragma unroll
        for (int r = 0; r < 4; r++) {
            int node = node0 + m0 + quad * 4 + r;
            if (node < n)
                hb[(size_t)node * 128 + c] = f2bs(acc[r] + bc);
        }
    }
}

// ---------------- fused GIN layer -----------------------------------------
__global__ __launch_bounds__(256, 6) void k_layer(
    const unsigned short* __restrict__ hb_in,
    unsigned short* __restrict__ hb_out,
    const int* __restrict__ rowptr, const int* __restrict__ adj,
    const short* __restrict__ pW1, const float* __restrict__ b1,
    const float* __restrict__ g1, const float* __restrict__ be1,
    const float* __restrict__ mu1, const float* __restrict__ va1,
    const short* __restrict__ pW2, const float* __restrict__ b2,
    const float* __restrict__ g2, const float* __restrict__ be2,
    const float* __restrict__ mu2, const float* __restrict__ va2,
    int n)
{
    __shared__ unsigned short sIn[32][136];    // bf16(h + sum nbr), pad 8
    __shared__ unsigned short sMid[32][264];   // bf16 MLP hidden, pad 8
    const int t = threadIdx.x;
    const int w = t >> 6;
    const int L = t & 63;
    const int node0 = blockIdx.x * 32;

    // ---- gather: wave w -> nodes w*8..w*8+7, processed in pairs with
    // interleaved edge loops (up to 8 independent loads in flight).
    const ushort2* hb2 = (const ushort2*)hb_in;
    for (int i = 0; i < 8; i += 2) {
        int mA = w * 8 + i;
        int nodeA = node0 + mA;
        int nodeB = nodeA + 1;
        bool vA = nodeA < n, vB = nodeB < n;
        float accA0[4] = {0.f, 0.f, 0.f, 0.f}, accA1[4] = {0.f, 0.f, 0.f, 0.f};
        float accB0[4] = {0.f, 0.f, 0.f, 0.f}, accB1[4] = {0.f, 0.f, 0.f, 0.f};
        int eA = 0, eAend = 0, eB = 0, eBend = 0;
        if (vA) {
            eA = rowptr[nodeA]; eAend = rowptr[nodeA + 1];
            ushort2 s = hb2[(size_t)nodeA * 64 + L];
            accA0[0] = bs2f(s.x); accA1[0] = bs2f(s.y);
        }
        if (vB) {
            eB = rowptr[nodeB]; eBend = rowptr[nodeB + 1];
            ushort2 s = hb2[(size_t)nodeB * 64 + L];
            accB0[0] = bs2f(s.x); accB1[0] = bs2f(s.y);
        }
        // joint path: 4+4 loads in flight
        while (eA + 4 <= eAend && eB + 4 <= eBend) {
            int sa[4], sb[4];
#pragma unroll
            for (int j = 0; j < 4; j++) { sa[j] = adj[eA + j]; sb[j] = adj[eB + j]; }
            ushort2 va[4], vb[4];
#pragma unroll
            for (int j = 0; j < 4; j++) {
                va[j] = hb2[(size_t)sa[j] * 64 + L];
                vb[j] = hb2[(size_t)sb[j] * 64 + L];
            }
#pragma unroll
            for (int j = 0; j < 4; j++) {
                accA0[j] += bs2f(va[j].x); accA1[j] += bs2f(va[j].y);
                accB0[j] += bs2f(vb[j].x); accB1[j] += bs2f(vb[j].y);
            }
            eA += 4; eB += 4;
        }
        // drain A
        while (eA + 4 <= eAend) {
            ushort2 va[4];
#pragma unroll
            for (int j = 0; j < 4; j++) va[j] = hb2[(size_t)adj[eA + j] * 64 + L];
#pragma unroll
            for (int j = 0; j < 4; j++) { accA0[j] += bs2f(va[j].x); accA1[j] += bs2f(va[j].y); }
            eA += 4;
        }
        while (eA < eAend) {
            ushort2 v = hb2[(size_t)adj[eA] * 64 + L];
            accA0[0] += bs2f(v.x); accA1[0] += bs2f(v.y);
            eA++;
        }
        // drain B
        while (eB + 4 <= eBend) {
            ushort2 vb[4];
#pragma unroll
            for (int j = 0; j < 4; j++) vb[j] = hb2[(size_t)adj[eB + j] * 64 + L];
#pragma unroll
            for (int j = 0; j < 4; j++) { accB0[j] += bs2f(vb[j].x); accB1[j] += bs2f(vb[j].y); }
            eB += 4;
        }
        while (eB < eBend) {
            ushort2 v = hb2[(size_t)adj[eB] * 64 + L];
            accB0[0] += bs2f(v.x); accB1[0] += bs2f(v.y);
            eB++;
        }
        ushort2 oA, oB;
        oA.x = f2bs(accA0[0] + accA0[1] + accA0[2] + accA0[3]);
        oA.y = f2bs(accA1[0] + accA1[1] + accA1[2] + accA1[3]);
        oB.x = f2bs(accB0[0] + accB0[1] + accB0[2] + accB0[3]);
        oB.y = f2bs(accB1[0] + accB1[1] + accB1[2] + accB1[3]);
        *(ushort2*)&sIn[mA][2 * L] = oA;
        *(ushort2*)&sIn[mA + 1][2 * L] = oB;
    }
    __syncthreads();

    const int quad = L >> 4;
    const int l16 = L & 15;
    const int m0 = (w & 1) * 16;

    // ---- phase 1: sMid = relu(BN1(sIn @ W1 + b1)), 32x256, K=128 ----
    {
        bf16x8 a[4];
#pragma unroll
        for (int kt = 0; kt < 4; kt++)
            a[kt] = *(const bf16x8*)&sIn[m0 + l16][kt * 32 + quad * 8];
        const bf16x8* base1 = (const bf16x8*)pW1;
        const int ntBase = (w >> 1) * 8;
        for (int nt = ntBase; nt < ntBase + 8; nt++) {
            f32x4 acc = {0.f, 0.f, 0.f, 0.f};
#pragma unroll
            for (int kt = 0; kt < 4; kt++) {
                bf16x8 b = base1[(size_t)(nt * 4 + kt) * 64 + L];
                acc = __builtin_amdgcn_mfma_f32_16x16x32_bf16(a[kt], b, acc, 0, 0, 0);
            }
            int c = nt * 16 + l16;
            float sc = g1[c] * rsqrtf(va1[c] + 1e-5f);
            float sh = (b1[c] - mu1[c]) * sc + be1[c];
#pragma unroll
            for (int r = 0; r < 4; r++) {
                float v = fmaxf(acc[r] * sc + sh, 0.f);
                sMid[m0 + quad * 4 + r][c] = f2bs(v);
            }
        }
    }
    __syncthreads();

    // ---- phase 2: m = relu(BN2(sMid @ W2 + b2)); hb_out = hb_in + m ----
    {
        f32x4 acc[4];
#pragma unroll
        for (int i = 0; i < 4; i++) acc[i] = (f32x4){0.f, 0.f, 0.f, 0.f};
        const bf16x8* base2 = (const bf16x8*)pW2;
        const int ntBase = (w >> 1) * 4;
#pragma unroll
        for (int kh = 0; kh < 2; kh++) {
            bf16x8 a[4];
#pragma unroll
            for (int kt = 0; kt < 4; kt++)
                a[kt] = *(const bf16x8*)&sMid[m0 + l16][(kh * 4 + kt) * 32 + quad * 8];
#pragma unroll
            for (int i = 0; i < 4; i++) {
#pragma unroll
                for (int kt = 0; kt < 4; kt++) {
                    bf16x8 b = base2[(size_t)((ntBase + i) * 8 + kh * 4 + kt) * 64 + L];
                    acc[i] = __builtin_amdgcn_mfma_f32_16x16x32_bf16(a[kt], b, acc[i], 0, 0, 0);
                }
            }
        }
#pragma unroll
        for (int i = 0; i < 4; i++) {
            int c = (ntBase + i) * 16 + l16;
            float sc = g2[c] * rsqrtf(va2[c] + 1e-5f);
            float sh = (b2[c] - mu2[c]) * sc + be2[c];
#pragma unroll
            for (int r = 0; r < 4; r++) {
                int node = node0 + m0 + quad * 4 + r;
                if (node < n) {
                    float o = fmaxf(acc[i][r] * sc + sh, 0.f);
                    float selfv = bs2f(hb_in[(size_t)node * 128 + c]);
                    hb_out[(size_t)node * 128 + c] = f2bs(selfv + o);
                }
            }
        }
    }
}

// ---------------- pooling: run-length over sorted batch (bf16 in) ---------
__global__ __launch_bounds__(256) void k_pool(const unsigned short* __restrict__ hb,
                                              const int* __restrict__ batch,
                                              float* __restrict__ pooled, int n)
{
    int c = threadIdx.x & 127;
    int half = threadIdx.x >> 7;
    int base = blockIdx.x * 128 + half * 64;
    float acc = 0.f;
    int curg = -1;
    for (int i = 0; i < 64; i++) {
        int node = base + i;
        if (node >= n) break;
        int g = batch[node];
        if (g != curg) {
            if (curg >= 0) atomicAdd(&pooled[(size_t)curg * 128 + c], acc);
            curg = g;
            acc = 0.f;
        }
        acc += bs2f(hb[(size_t)node * 128 + c]);
    }
    if (curg >= 0) atomicAdd(&pooled[(size_t)curg * 128 + c], acc);
}

__global__ __launch_bounds__(128) void k_head(const float* __restrict__ pooled,
                                              const float* __restrict__ W1,
                                              const float* __restrict__ b1,
                                              const float* __restrict__ W2,
                                              const float* __restrict__ b2,
                                              float* __restrict__ out)
{
    __shared__ float sp[128];
    __shared__ float st[128];
    int t = threadIdx.x;
    int g = blockIdx.x;
    sp[t] = pooled[(size_t)g * 128 + t];
    __syncthreads();
    float a = 0.f;
    for (int k = 0; k < 128; k++) a += sp[k] * W1[k * 128 + t];
    st[t] = fmaxf(a + b1[t], 0.f);
    __syncthreads();
    float o = 0.f;
    for (int k = 0; k < 128; k++) o += st[k] * W2[k * 128 + t];
    out[(size_t)g * 128 + t] = o + b2[t];
}

extern "C" void kernel_launch(void* const* d_in, const int* in_sizes, int n_in,
                              void* d_out, int out_size, void* d_ws, size_t ws_size,
                              hipStream_t stream)
{
    const float* x     = (const float*)d_in[0];
    const int*   ei    = (const int*)d_in[1];
    const int*   batch = (const int*)d_in[2];
    const float* W0    = (const float*)d_in[3];
    const float* b0    = (const float*)d_in[4];
    const float* mlpW1 = (const float*)d_in[5];
    const float* mlpb1 = (const float*)d_in[6];
    const float* bn1g  = (const float*)d_in[7];
    const float* bn1b  = (const float*)d_in[8];
    const float* bn1m  = (const float*)d_in[9];
    const float* bn1v  = (const float*)d_in[10];
    const float* mlpW2 = (const float*)d_in[11];
    const float* mlpb2 = (const float*)d_in[12];
    const float* ng    = (const float*)d_in[13];
    const float* nb    = (const float*)d_in[14];
    const float* nm    = (const float*)d_in[15];
    const float* nv    = (const float*)d_in[16];
    const float* W1    = (const float*)d_in[17];
    const float* b1    = (const float*)d_in[18];
    const float* W2    = (const float*)d_in[19];
    const float* b2    = (const float*)d_in[20];
    float* out = (float*)d_out;

    const int N = in_sizes[0] / 128;
    const int E = in_sizes[1] / 2;
    const int G = out_size / 128;
    const int* srcv = ei;
    const int* dstv = ei + E;

    // workspace layout
    float* pooled = (float*)d_ws;                               // G*128 f32
    unsigned short* hbA = (unsigned short*)(pooled + (size_t)G * 128); // N*128
    unsigned short* hbB = hbA + (size_t)N * 128;                // N*128
    short* pW1 = (short*)(hbB + (size_t)N * 128);               // 4*128*256
    short* pW2 = pW1 + 131072;                                  // 4*256*128
    short* pW0 = pW2 + 131072;                                  // 128*128
    int* ints  = (int*)(pW0 + 16384);
    int* deg      = ints;
    int* rowptr   = ints + N;
    int* cursor   = ints + 2 * N + 1;
    int* partials = ints + 3 * N + 1;                           // 256
    int* adj      = ints + 3 * N + 1 + 256;                     // E

    const int nodeBlocks = (N + 31) / 32;
    const int nbScan = (N + 255) / 256;

    // ---- CSR build + weight packing ----
    hipMemsetAsync(deg, 0, (size_t)N * sizeof(int), stream);
    k_hist<<<(E + 255) / 256, 256, 0, stream>>>(dstv, deg, E);
    k_scanA<<<nbScan, 256, 0, stream>>>(deg, partials, N);
    k_scanC<<<nbScan, 256, 0, stream>>>(deg, partials, rowptr, cursor, N, nbScan);
    k_fill<<<(E + 255) / 256, 256, 0, stream>>>(srcv, dstv, cursor, adj, E);
    k_pack<<<(4 * 16 * 4 * 64 + 255) / 256, 256, 0, stream>>>(mlpW1, pW1, 4, 4, 16);
    k_pack<<<(4 * 8 * 8 * 64 + 255) / 256, 256, 0, stream>>>(mlpW2, pW2, 4, 8, 8);
    k_pack<<<(1 * 8 * 4 * 64 + 255) / 256, 256, 0, stream>>>(W0, pW0, 1, 4, 8);

    // ---- encoder ----
    k_encoder<<<nodeBlocks, 256, 0, stream>>>(x, pW0, b0, hbA, N);

    // ---- layers (bf16 residual, ping-pong) ----
    unsigned short* hc = hbA;
    unsigned short* hn = hbB;
    for (int l = 0; l < 4; l++) {
        k_layer<<<nodeBlocks, 256, 0, stream>>>(
            hc, hn, rowptr, adj,
            pW1 + (size_t)l * 32768, mlpb1 + (size_t)l * 256,
            bn1g + (size_t)l * 256, bn1b + (size_t)l * 256,
            bn1m + (size_t)l * 256, bn1v + (size_t)l * 256,
            pW2 + (size_t)l * 32768, mlpb2 + (size_t)l * 128,
            ng + (size_t)l * 128, nb + (size_t)l * 128,
            nm + (size_t)l * 128, nv + (size_t)l * 128,
            N);
        unsigned short* tmp = hc; hc = hn; hn = tmp;
    }

    // ---- pool + head (final stream is hc) ----
    hipMemsetAsync(pooled, 0, (size_t)G * 128 * sizeof(float), stream);
    k_pool<<<(N + 127) / 128, 256, 0, stream>>>(hc, batch, pooled, N);
    k_head<<<G, 128, 0, stream>>>(pooled, W1, b1, W2, b2, out);
}